// Round 9
// baseline (163.717 us; speedup 1.0000x reference)
//
#include <hip/hip_runtime.h>
#include <hip/hip_bf16.h>
#include <math.h>

#define CHUNK 1024

typedef __attribute__((ext_vector_type(8))) short bf16x8;
typedef __attribute__((ext_vector_type(4))) float f32x4;

__device__ __forceinline__ unsigned short f2bf(float f) {
    unsigned u = __float_as_uint(f);
    unsigned r = ((u >> 16) & 1u) + 0x7fffu;   // RNE
    return (unsigned short)((u + r) >> 16);
}
__device__ __forceinline__ float bf2f(unsigned short s) {
    return __uint_as_float((unsigned)s << 16);
}

// ---- prep ------------------------------------------------------------------
// block 0: W -> bf16 MFMA B-fragment order (granule gi = kg*128 + row;
//          k = (kg>>2)*32 + (e>>2)*16 + (kg&3)*4 + (e&3))
// block 1: score B-matrix wsdB (16 cols x 128 k, bf16 hi/lo split):
//          col 0-3 srcHi[hd], 4-7 dstHi[hd], 8-11 srcLo, 12-15 dstLo
//          + consts[8] = bias . att halves
// blocks 2+: zero counts
__global__ __launch_bounds__(256) void k_prep(const float* __restrict__ W,
                                              const float* __restrict__ bias,
                                              const float* __restrict__ att,
                                              unsigned short* __restrict__ Wb16,
                                              unsigned short* __restrict__ wsdB,
                                              float* __restrict__ consts,
                                              int* __restrict__ counts, int N) {
    const int t = threadIdx.x;
    const int bid = blockIdx.x;
    if (bid == 0) {
#pragma unroll
        for (int q = 0; q < 8; ++q) {
            int gi = q * 256 + t;
            int kg = gi >> 7, row = gi & 127;
            int kbase = (kg >> 2) * 32 + (kg & 3) * 4;
            unsigned pk[4];
#pragma unroll
            for (int p = 0; p < 4; ++p) {
                int e0 = 2 * p, e1 = 2 * p + 1;
                float v0 = W[(size_t)row * 128 + kbase + (e0 >> 2) * 16 + (e0 & 3)];
                float v1 = W[(size_t)row * 128 + kbase + (e1 >> 2) * 16 + (e1 & 3)];
                pk[p] = ((unsigned)f2bf(v1) << 16) | f2bf(v0);
            }
            *reinterpret_cast<uint4*>(&Wb16[(size_t)gi * 8]) =
                make_uint4(pk[0], pk[1], pk[2], pk[3]);
        }
    } else if (bid == 1) {
        int kg = t >> 4, la = t & 15;
        int hd = la & 3;
        int isDst = (la >> 2) & 1;
        int isLo = la >> 3;
        unsigned short vals[8];
#pragma unroll
        for (int e = 0; e < 8; ++e) {
            int k = (kg >> 2) * 32 + (e >> 2) * 16 + (kg & 3) * 4 + (e & 3);
            float w = 0.f;
            for (int j = 0; j < 32; ++j)
                w += W[(size_t)(hd * 32 + j) * 128 + k] * att[hd * 65 + isDst * 32 + j];
            unsigned short hi = f2bf(w);
            vals[e] = isLo ? f2bf(w - bf2f(hi)) : hi;
        }
        int gi = kg * 16 + la;
        unsigned pk[4];
#pragma unroll
        for (int p = 0; p < 4; ++p)
            pk[p] = ((unsigned)vals[2 * p + 1] << 16) | vals[2 * p];
        *reinterpret_cast<uint4*>(&wsdB[(size_t)gi * 8]) =
            make_uint4(pk[0], pk[1], pk[2], pk[3]);
        if (t < 8) {
            int chd = t & 3, cIsD = t >> 2;
            float c = 0.f;
            for (int j = 0; j < 32; ++j)
                c += bias[chd * 32 + j] * att[chd * 65 + cIsD * 32 + j];
            consts[t] = c;
        }
    } else {
        int i = ((bid - 2) * 256 + t) * 4;
        if (i < N) *reinterpret_cast<int4*>(&counts[i]) = make_int4(0, 0, 0, 0);
    }
}

// ---- mega: MFMA GEMM (bf16 in / fp32 acc) + MFMA scores + hist -------------
__global__ __launch_bounds__(256) void k_mega(
        const float* __restrict__ h, const unsigned short* __restrict__ Wb16,
        const unsigned short* __restrict__ wsdB, const float* __restrict__ consts,
        const float* __restrict__ bias,
        const int* __restrict__ dstI, int* __restrict__ counts,
        unsigned short* __restrict__ zb16,
        float* __restrict__ s_src, float* __restrict__ s_dst,
        int N, int E, int gemmBlocks) {
    __shared__ short hS[16 * 64 * 8];    // 16 KB
    const int t = threadIdx.x;
    const int bid = blockIdx.x;

    if (bid >= gemmBlocks) {             // ---- histogram (4 edges/thread) ----
        int base = (bid - gemmBlocks) * 1024 + t;
#pragma unroll
        for (int q = 0; q < 4; ++q) {
            int e = base + q * 256;
            if (e < E) atomicAdd(&counts[dstI[e]], 1);
        }
        return;
    }

    // ---- GEMM block: 64 nodes x 128 outs ----
    const int n0 = bid * 64;
#pragma unroll
    for (int q = 0; q < 8; ++q) {
        int f = q * 256 + t;
        int node = f >> 5;
        int k4 = (f & 31) * 4;
        int ks = k4 >> 5, rr = k4 & 31;
        int half = rr >> 4, g = (rr & 15) >> 2;
        int kg = ks * 4 + g;
        int slot = kg * 64 + (node ^ (kg & 7));
        int hn = n0 + node; if (hn > N - 1) hn = N - 1;
        float4 v = *reinterpret_cast<const float4*>(&h[(size_t)hn * 128 + k4]);
        uint2 pk = make_uint2(((unsigned)f2bf(v.y) << 16) | f2bf(v.x),
                              ((unsigned)f2bf(v.w) << 16) | f2bf(v.z));
        *reinterpret_cast<uint2*>(&hS[slot * 8 + half * 4]) = pk;
    }
    __syncthreads();

    const int wv = t >> 6, l = t & 63;
    const int la = l & 15, lb = l >> 4;
    const int nbase = wv * 16;

    bf16x8 afr[4], sfr[4];
#pragma unroll
    for (int ks = 0; ks < 4; ++ks) {
        int kg = ks * 4 + lb;
        int slot = kg * 64 + ((nbase + la) ^ (kg & 7));
        afr[ks] = *reinterpret_cast<const bf16x8*>(&hS[slot * 8]);
        sfr[ks] = *reinterpret_cast<const bf16x8*>(&wsdB[(size_t)(kg * 16 + la) * 8]);
    }

#pragma unroll
    for (int ot = 0; ot < 8; ++ot) {
        f32x4 acc = {0.f, 0.f, 0.f, 0.f};
#pragma unroll
        for (int ks = 0; ks < 4; ++ks) {
            int gi = (ks * 4 + lb) * 128 + ot * 16 + la;
            bf16x8 bfr = *reinterpret_cast<const bf16x8*>(&Wb16[(size_t)gi * 8]);
            acc = __builtin_amdgcn_mfma_f32_16x16x32_bf16(afr[ks], bfr, acc, 0, 0, 0);
        }
        const int col = ot * 16 + la;
        float bv = bias[col];
#pragma unroll
        for (int r = 0; r < 4; ++r) {
            int node = n0 + nbase + lb * 4 + r;
            if (node < N) zb16[(size_t)node * 128 + col] = f2bf(acc[r] + bv);
        }
    }

    // scores: one MFMA chain over the 16-col wsdB matrix (hi+lo columns)
    f32x4 accS = {0.f, 0.f, 0.f, 0.f};
#pragma unroll
    for (int ks = 0; ks < 4; ++ks)
        accS = __builtin_amdgcn_mfma_f32_16x16x32_bf16(afr[ks], sfr[ks], accS, 0, 0, 0);

    float cst = consts[la & 7];
#pragma unroll
    for (int r = 0; r < 4; ++r) {
        float tot = accS[r] + __shfl_xor(accS[r], 8);   // hi + lo column
        if (la < 8) {
            int node = n0 + nbase + lb * 4 + r;
            if (node < N) {
                float* dstp = (la < 4) ? s_src : s_dst;
                dstp[(size_t)node * 4 + (la & 3)] = tot + cst;
            }
        }
    }
}

// ------------- scan with 4-aligned bucket starts ----------------------------
__global__ __launch_bounds__(256) void k_scan_block(const int* __restrict__ counts,
                                                    int* __restrict__ offs,
                                                    int* __restrict__ bsum, int N) {
    __shared__ int sd[256];
    int t = threadIdx.x, b = blockIdx.x;
    int i0 = b * CHUNK + t * 4;
    int p[4];
#pragma unroll
    for (int j = 0; j < 4; ++j)
        p[j] = (i0 + j < N) ? ((counts[i0 + j] + 3) & ~3) : 0;
    int tsum = p[0] + p[1] + p[2] + p[3];
    sd[t] = tsum;
    __syncthreads();
    for (int d = 1; d < 256; d <<= 1) {
        int v = (t >= d) ? sd[t - d] : 0;
        __syncthreads();
        sd[t] += v;
        __syncthreads();
    }
    int pre = sd[t] - tsum;
#pragma unroll
    for (int j = 0; j < 4; ++j) {
        if (i0 + j < N) offs[i0 + j] = pre;
        pre += p[j];
    }
    if (t == 255) bsum[b] = sd[255];
}

// addoff with inline top-scan (nb <= 64)
__global__ __launch_bounds__(256) void k_addoff(int* __restrict__ offs,
                                                int* __restrict__ cursor,
                                                const int* __restrict__ bsum,
                                                int N, int nb) {
    __shared__ int base_s;
    int t = threadIdx.x;
    int i = blockIdx.x * 256 + t;
    int chunk = (blockIdx.x * 256) >> 10;
    if (t < 64) {
        int v = (t < chunk && t < nb) ? bsum[t] : 0;
#pragma unroll
        for (int off = 1; off < 64; off <<= 1) v += __shfl_xor(v, off);
        if (t == 0) base_s = v;
    }
    __syncthreads();
    if (i < N) {
        int o = offs[i] + base_s;
        offs[i] = o;
        cursor[i] = o;
    }
}

// ------------- scatter: 2 edges/thread, single 16B packed write -------------
__global__ __launch_bounds__(256) void k_scatter(const int* __restrict__ src,
                                                 const int* __restrict__ dst,
                                                 const float* __restrict__ ef,
                                                 const float* __restrict__ att,
                                                 const float* __restrict__ s_src,
                                                 const float* __restrict__ s_dst,
                                                 int* __restrict__ cursor,
                                                 int4* __restrict__ epack, int E) {
    int gid = blockIdx.x * 256 + threadIdx.x;
    int e0 = gid * 2;
    if (e0 >= E) return;
    const bool has1 = (e0 + 1) < E;
    int2 s2 = *reinterpret_cast<const int2*>(&src[e0]);
    int2 d2 = *reinterpret_cast<const int2*>(&dst[e0]);
    float2 f2v = *reinterpret_cast<const float2*>(&ef[e0]);
    float aE0 = att[64], aE1 = att[129], aE2 = att[194], aE3 = att[259];

    float4 ssA = *reinterpret_cast<const float4*>(&s_src[(size_t)s2.x * 4]);
    float4 sdA = *reinterpret_cast<const float4*>(&s_dst[(size_t)d2.x * 4]);
    float4 ssB, sdB;
    if (has1) {
        ssB = *reinterpret_cast<const float4*>(&s_src[(size_t)s2.y * 4]);
        sdB = *reinterpret_cast<const float4*>(&s_dst[(size_t)d2.y * 4]);
    }
    int posA = atomicAdd(&cursor[d2.x], 1);
    int posB = has1 ? atomicAdd(&cursor[d2.y], 1) : 0;

    {
        float sc0 = ssA.x + sdA.x + f2v.x * aE0;
        float sc1 = ssA.y + sdA.y + f2v.x * aE1;
        float sc2 = ssA.z + sdA.z + f2v.x * aE2;
        float sc3 = ssA.w + sdA.w + f2v.x * aE3;
        sc0 = sc0 >= 0.f ? sc0 : 0.2f * sc0;  sc1 = sc1 >= 0.f ? sc1 : 0.2f * sc1;
        sc2 = sc2 >= 0.f ? sc2 : 0.2f * sc2;  sc3 = sc3 >= 0.f ? sc3 : 0.2f * sc3;
        float a0 = expf(fminf(fmaxf(sc0, -20.f), 20.f));
        float a1 = expf(fminf(fmaxf(sc1, -20.f), 20.f));
        float a2 = expf(fminf(fmaxf(sc2, -20.f), 20.f));
        float a3 = expf(fminf(fmaxf(sc3, -20.f), 20.f));
        epack[posA] = make_int4(s2.x,
            (int)(((unsigned)f2bf(a1) << 16) | f2bf(a0)),
            (int)(((unsigned)f2bf(a3) << 16) | f2bf(a2)), 0);
    }
    if (has1) {
        float sc0 = ssB.x + sdB.x + f2v.y * aE0;
        float sc1 = ssB.y + sdB.y + f2v.y * aE1;
        float sc2 = ssB.z + sdB.z + f2v.y * aE2;
        float sc3 = ssB.w + sdB.w + f2v.y * aE3;
        sc0 = sc0 >= 0.f ? sc0 : 0.2f * sc0;  sc1 = sc1 >= 0.f ? sc1 : 0.2f * sc1;
        sc2 = sc2 >= 0.f ? sc2 : 0.2f * sc2;  sc3 = sc3 >= 0.f ? sc3 : 0.2f * sc3;
        float a0 = expf(fminf(fmaxf(sc0, -20.f), 20.f));
        float a1 = expf(fminf(fmaxf(sc1, -20.f), 20.f));
        float a2 = expf(fminf(fmaxf(sc2, -20.f), 20.f));
        float a3 = expf(fminf(fmaxf(sc3, -20.f), 20.f));
        epack[posB] = make_int4(s2.y,
            (int)(((unsigned)f2bf(a1) << 16) | f2bf(a0)),
            (int)(((unsigned)f2bf(a3) << 16) | f2bf(a2)), 0);
    }
}

// ------------- fused: aggregate (bf16 z) + residual + LN + ELU --------------
__global__ __launch_bounds__(256) void k_agg_final(const int* __restrict__ offs,
                                                   const int* __restrict__ counts,
                                                   const int4* __restrict__ epack,
                                                   const unsigned int* __restrict__ zb,
                                                   const float* __restrict__ g,
                                                   const float* __restrict__ bparm,
                                                   float* __restrict__ out, int N) {
    int wave = threadIdx.x >> 6, lane = threadIdx.x & 63;
    int n = blockIdx.x * 4 + wave;
    if (n >= N) return;
    const int start = offs[n], len = counts[n];
    const int hd = lane >> 4;
    const int c = lane * 2;
    float ax = 0.f, ay = 0.f, da = 0.f;
    float bx = 0.f, by = 0.f, db = 0.f;
    int i = start;
    const int end = start + len;
#define UNPK(P, AV) { unsigned u = (hd & 2) ? (unsigned)(P).z : (unsigned)(P).y; \
    AV = __uint_as_float((hd & 1) ? (u & 0xffff0000u) : (u << 16)); }
    for (; i + 7 < end; i += 8) {
        int4 p0 = epack[i + 0], p1 = epack[i + 1], p2 = epack[i + 2], p3 = epack[i + 3];
        int4 p4 = epack[i + 4], p5 = epack[i + 5], p6 = epack[i + 6], p7 = epack[i + 7];
        float a0, a1, a2, a3, a4, a5, a6, a7;
        UNPK(p0, a0) UNPK(p1, a1) UNPK(p2, a2) UNPK(p3, a3)
        UNPK(p4, a4) UNPK(p5, a5) UNPK(p6, a6) UNPK(p7, a7)
        unsigned q0 = zb[(size_t)p0.x * 64 + lane];
        unsigned q1 = zb[(size_t)p1.x * 64 + lane];
        unsigned q2 = zb[(size_t)p2.x * 64 + lane];
        unsigned q3 = zb[(size_t)p3.x * 64 + lane];
        unsigned q4 = zb[(size_t)p4.x * 64 + lane];
        unsigned q5 = zb[(size_t)p5.x * 64 + lane];
        unsigned q6 = zb[(size_t)p6.x * 64 + lane];
        unsigned q7 = zb[(size_t)p7.x * 64 + lane];
        ax += __uint_as_float(q0 << 16) * a0; ay += __uint_as_float(q0 & 0xffff0000u) * a0; da += a0;
        bx += __uint_as_float(q1 << 16) * a1; by += __uint_as_float(q1 & 0xffff0000u) * a1; db += a1;
        ax += __uint_as_float(q2 << 16) * a2; ay += __uint_as_float(q2 & 0xffff0000u) * a2; da += a2;
        bx += __uint_as_float(q3 << 16) * a3; by += __uint_as_float(q3 & 0xffff0000u) * a3; db += a3;
        ax += __uint_as_float(q4 << 16) * a4; ay += __uint_as_float(q4 & 0xffff0000u) * a4; da += a4;
        bx += __uint_as_float(q5 << 16) * a5; by += __uint_as_float(q5 & 0xffff0000u) * a5; db += a5;
        ax += __uint_as_float(q6 << 16) * a6; ay += __uint_as_float(q6 & 0xffff0000u) * a6; da += a6;
        bx += __uint_as_float(q7 << 16) * a7; by += __uint_as_float(q7 & 0xffff0000u) * a7; db += a7;
    }
    for (; i < end; ++i) {
        int4 p0 = epack[i];
        float a0; UNPK(p0, a0)
        unsigned q0 = zb[(size_t)p0.x * 64 + lane];
        ax += __uint_as_float(q0 << 16) * a0;
        ay += __uint_as_float(q0 & 0xffff0000u) * a0;
        da += a0;
    }
#undef UNPK

    float inv = 1.f / (da + db + 1e-6f);
    unsigned pz = zb[(size_t)n * 64 + lane];
    float x0 = (ax + bx) * inv + __uint_as_float(pz << 16);
    float x1 = (ay + by) * inv + __uint_as_float(pz & 0xffff0000u);
    float s = x0 + x1;
    for (int off = 32; off; off >>= 1) s += __shfl_xor(s, off);
    float mu = s * (1.f / 128.f);
    float d0 = x0 - mu, d1 = x1 - mu;
    float q = d0 * d0 + d1 * d1;
    for (int off = 32; off; off >>= 1) q += __shfl_xor(q, off);
    float rstd = rsqrtf(q * (1.f / 128.f) + 1e-5f);
    float2 gg = *reinterpret_cast<const float2*>(&g[c]);
    float2 bb = *reinterpret_cast<const float2*>(&bparm[c]);
    float y0 = d0 * rstd * gg.x + bb.x;
    float y1 = d1 * rstd * gg.y + bb.y;
    y0 = y0 > 0.f ? y0 : expf(y0) - 1.f;
    y1 = y1 > 0.f ? y1 : expf(y1) - 1.f;
    *reinterpret_cast<float2*>(&out[(size_t)n * 128 + c]) = make_float2(y0, y1);
}

extern "C" void kernel_launch(void* const* d_in, const int* in_sizes, int n_in,
                              void* d_out, int out_size, void* d_ws, size_t ws_size,
                              hipStream_t stream) {
    const float* h   = (const float*)d_in[0];
    const int*   ei  = (const int*)d_in[1];
    const float* ef  = (const float*)d_in[2];
    const float* Ww  = (const float*)d_in[3];
    const float* Wb  = (const float*)d_in[4];
    const float* att = (const float*)d_in[5];
    const float* lng = (const float*)d_in[6];
    const float* lnb = (const float*)d_in[7];
    float* out = (float*)d_out;

    const int N = in_sizes[0] / 128;   // 50000
    const int E = in_sizes[1] / 2;     // 800000
    const int* src = ei;
    const int* dst = ei + E;
    const int nb = (N + CHUNK - 1) / CHUNK;   // 49 (<=64 required)
    const int sortedCap = E + 3 * N + 64;

    char* ws = (char*)d_ws;
    unsigned short* zb16     = (unsigned short*)ws; ws += (size_t)N * 128 * 2;
    unsigned short* Wb16     = (unsigned short*)ws; ws += (size_t)128 * 128 * 2;
    unsigned short* wsdB     = (unsigned short*)ws; ws += (size_t)16 * 16 * 8 * 2;
    float*          consts   = (float*)ws;          ws += (size_t)8 * 4;
    float*          s_src    = (float*)ws;          ws += (size_t)N * 4 * 4;
    float*          s_dst    = (float*)ws;          ws += (size_t)N * 4 * 4;
    int*            counts   = (int*)ws;            ws += (size_t)N * 4;
    int*            offs     = (int*)ws;            ws += (size_t)N * 4;
    int*            cursor   = (int*)ws;            ws += (size_t)N * 4;
    int*            bsum     = (int*)ws;            ws += (size_t)64 * 4;
    int4*           epack    = (int4*)ws;           ws += (size_t)sortedCap * 16;

    const int zeroBlocks = (N + 1023) / 1024;        // 49
    k_prep<<<2 + zeroBlocks, 256, 0, stream>>>(Ww, Wb, att, Wb16, wsdB, consts, counts, N);

    const int gemmBlocks = (N + 63) / 64;            // 782
    const int histBlocks = (E + 1023) / 1024;        // 782
    k_mega<<<gemmBlocks + histBlocks, 256, 0, stream>>>(
        h, Wb16, wsdB, consts, Wb, dst, counts, zb16, s_src, s_dst, N, E, gemmBlocks);
    k_scan_block<<<nb, 256, 0, stream>>>(counts, offs, bsum, N);
    k_addoff<<<(N + 255) / 256, 256, 0, stream>>>(offs, cursor, bsum, N, nb);
    k_scatter<<<(E / 2 + 255) / 256, 256, 0, stream>>>(src, dst, ef, att, s_src, s_dst, cursor, epack, E);
    k_agg_final<<<(N + 3) / 4, 256, 0, stream>>>(offs, counts, epack,
                                                 (const unsigned int*)zb16, lng, lnb, out, N);
}

// Round 10
// 159.375 us; speedup vs baseline: 1.0272x; 1.0272x over previous
//
#include <hip/hip_runtime.h>
#include <hip/hip_bf16.h>
#include <math.h>

#define CHUNK 1024

typedef __attribute__((ext_vector_type(8))) short bf16x8;
typedef __attribute__((ext_vector_type(4))) float f32x4;

__device__ __forceinline__ unsigned short f2bf(float f) {
    unsigned u = __float_as_uint(f);
    unsigned r = ((u >> 16) & 1u) + 0x7fffu;   // RNE
    return (unsigned short)((u + r) >> 16);
}
__device__ __forceinline__ float bf2f(unsigned short s) {
    return __uint_as_float((unsigned)s << 16);
}
__device__ __forceinline__ float bfL(unsigned u) { return __uint_as_float(u << 16); }
__device__ __forceinline__ float bfH(unsigned u) { return __uint_as_float(u & 0xffff0000u); }

// ---- prep ------------------------------------------------------------------
// block 0: W -> bf16 MFMA fragment order (granule gi = kg*128 + row;
//          k = (kg>>2)*32 + (e>>2)*16 + (kg&3)*4 + (e&3))
// block 1: score matrix wsdB (16 comps x 128 k, bf16 hi/lo split):
//          comp 0-3 srcHi[hd], 4-7 dstHi, 8-11 srcLo, 12-15 dstLo
//          + consts[8] = bias . att halves (0-3 src, 4-7 dst)
// blocks 2+: zero counts
__global__ __launch_bounds__(256) void k_prep(const float* __restrict__ W,
                                              const float* __restrict__ bias,
                                              const float* __restrict__ att,
                                              unsigned short* __restrict__ Wb16,
                                              unsigned short* __restrict__ wsdB,
                                              float* __restrict__ consts,
                                              int* __restrict__ counts, int N) {
    const int t = threadIdx.x;
    const int bid = blockIdx.x;
    if (bid == 0) {
#pragma unroll
        for (int q = 0; q < 8; ++q) {
            int gi = q * 256 + t;
            int kg = gi >> 7, row = gi & 127;
            int kbase = (kg >> 2) * 32 + (kg & 3) * 4;
            unsigned pk[4];
#pragma unroll
            for (int p = 0; p < 4; ++p) {
                int e0 = 2 * p, e1 = 2 * p + 1;
                float v0 = W[(size_t)row * 128 + kbase + (e0 >> 2) * 16 + (e0 & 3)];
                float v1 = W[(size_t)row * 128 + kbase + (e1 >> 2) * 16 + (e1 & 3)];
                pk[p] = ((unsigned)f2bf(v1) << 16) | f2bf(v0);
            }
            *reinterpret_cast<uint4*>(&Wb16[(size_t)gi * 8]) =
                make_uint4(pk[0], pk[1], pk[2], pk[3]);
        }
    } else if (bid == 1) {
        int kg = t >> 4, la = t & 15;
        int hd = la & 3;
        int isDst = (la >> 2) & 1;
        int isLo = la >> 3;
        unsigned short vals[8];
#pragma unroll
        for (int e = 0; e < 8; ++e) {
            int k = (kg >> 2) * 32 + (e >> 2) * 16 + (kg & 3) * 4 + (e & 3);
            float w = 0.f;
            for (int j = 0; j < 32; ++j)
                w += W[(size_t)(hd * 32 + j) * 128 + k] * att[hd * 65 + isDst * 32 + j];
            unsigned short hi = f2bf(w);
            vals[e] = isLo ? f2bf(w - bf2f(hi)) : hi;
        }
        int gi = kg * 16 + la;
        unsigned pk[4];
#pragma unroll
        for (int p = 0; p < 4; ++p)
            pk[p] = ((unsigned)vals[2 * p + 1] << 16) | vals[2 * p];
        *reinterpret_cast<uint4*>(&wsdB[(size_t)gi * 8]) =
            make_uint4(pk[0], pk[1], pk[2], pk[3]);
        if (t < 8) {
            int chd = t & 3, cIsD = t >> 2;
            float c = 0.f;
            for (int j = 0; j < 32; ++j)
                c += bias[chd * 32 + j] * att[chd * 65 + cIsD * 32 + j];
            consts[t] = c;
        }
    } else {
        int i = ((bid - 2) * 256 + t) * 4;
        if (i < N) *reinterpret_cast<int4*>(&counts[i]) = make_int4(0, 0, 0, 0);
    }
}

// ---- mega: MFMA GEMM (swapped operands: D[col][node]) + scores + hist ------
__global__ __launch_bounds__(256) void k_mega(
        const float* __restrict__ h, const unsigned short* __restrict__ Wb16,
        const unsigned short* __restrict__ wsdB, const float* __restrict__ consts,
        const float* __restrict__ bias,
        const int* __restrict__ dstI, int* __restrict__ counts,
        unsigned short* __restrict__ zb16,
        float* __restrict__ s_src, float* __restrict__ s_dst,
        int N, int E, int gemmBlocks) {
    __shared__ short hS[16 * 64 * 8];    // 16 KB
    const int t = threadIdx.x;
    const int bid = blockIdx.x;

    if (bid >= gemmBlocks) {             // ---- histogram (4 edges/thread) ----
        int base = (bid - gemmBlocks) * 1024 + t;
#pragma unroll
        for (int q = 0; q < 4; ++q) {
            int e = base + q * 256;
            if (e < E) atomicAdd(&counts[dstI[e]], 1);
        }
        return;
    }

    // ---- GEMM block: 64 nodes x 128 outs ----
    const int n0 = bid * 64;
#pragma unroll
    for (int q = 0; q < 8; ++q) {
        int f = q * 256 + t;
        int node = f >> 5;
        int k4 = (f & 31) * 4;
        int ks = k4 >> 5, rr = k4 & 31;
        int half = rr >> 4, g = (rr & 15) >> 2;
        int kg = ks * 4 + g;
        int slot = kg * 64 + (node ^ (kg & 7));
        int hn = n0 + node; if (hn > N - 1) hn = N - 1;
        float4 v = *reinterpret_cast<const float4*>(&h[(size_t)hn * 128 + k4]);
        uint2 pk = make_uint2(((unsigned)f2bf(v.y) << 16) | f2bf(v.x),
                              ((unsigned)f2bf(v.w) << 16) | f2bf(v.z));
        *reinterpret_cast<uint2*>(&hS[slot * 8 + half * 4]) = pk;
    }
    __syncthreads();

    const int wv = t >> 6, l = t & 63;
    const int la = l & 15, lb = l >> 4;
    const int nbase = wv * 16;
    const int node = n0 + nbase + la;     // this lane's node (B-operand index)

    bf16x8 hfr[4];
#pragma unroll
    for (int ks = 0; ks < 4; ++ks) {
        int kg = ks * 4 + lb;
        int slot = kg * 64 + ((nbase + la) ^ (kg & 7));
        hfr[ks] = *reinterpret_cast<const bf16x8*>(&hS[slot * 8]);
    }

    // scores: A = wsdB (16 comps), B = h  ->  D[comp][node]
    f32x4 accS = {0.f, 0.f, 0.f, 0.f};
#pragma unroll
    for (int ks = 0; ks < 4; ++ks) {
        int kg = ks * 4 + lb;
        bf16x8 sfr = *reinterpret_cast<const bf16x8*>(&wsdB[(size_t)(kg * 16 + la) * 8]);
        accS = __builtin_amdgcn_mfma_f32_16x16x32_bf16(sfr, hfr[ks], accS, 0, 0, 0);
    }
    float t0 = accS[0] + __shfl_xor(accS[0], 32);   // hi + lo (lb 0<->2, 1<->3)
    float t1 = accS[1] + __shfl_xor(accS[1], 32);
    float t2 = accS[2] + __shfl_xor(accS[2], 32);
    float t3 = accS[3] + __shfl_xor(accS[3], 32);
    if (lb < 2 && node < N) {
        float4 cv = *reinterpret_cast<const float4*>(&consts[lb * 4]);
        float4 o = make_float4(t0 + cv.x, t1 + cv.y, t2 + cv.z, t3 + cv.w);
        float* dp = (lb == 0) ? s_src : s_dst;
        *reinterpret_cast<float4*>(&dp[(size_t)node * 4]) = o;
    }

    // GEMM: A = W-tile (16 cols), B = h  ->  lane holds 4 contiguous cols
#pragma unroll
    for (int ot = 0; ot < 8; ++ot) {
        f32x4 acc = {0.f, 0.f, 0.f, 0.f};
#pragma unroll
        for (int ks = 0; ks < 4; ++ks) {
            int kg = ks * 4 + lb;
            bf16x8 wfr = *reinterpret_cast<const bf16x8*>(&Wb16[((size_t)kg * 128 + ot * 16 + la) * 8]);
            acc = __builtin_amdgcn_mfma_f32_16x16x32_bf16(wfr, hfr[ks], acc, 0, 0, 0);
        }
        int colb = ot * 16 + lb * 4;
        float4 bq = *reinterpret_cast<const float4*>(&bias[colb]);
        if (node < N) {
            uint2 pk = make_uint2(
                ((unsigned)f2bf(acc[1] + bq.y) << 16) | f2bf(acc[0] + bq.x),
                ((unsigned)f2bf(acc[3] + bq.w) << 16) | f2bf(acc[2] + bq.z));
            *reinterpret_cast<uint2*>(&zb16[(size_t)node * 128 + colb]) = pk;
        }
    }
}

// ------------- scan with 4-aligned bucket starts ----------------------------
__global__ __launch_bounds__(256) void k_scan_block(const int* __restrict__ counts,
                                                    int* __restrict__ offs,
                                                    int* __restrict__ bsum, int N) {
    __shared__ int sd[256];
    int t = threadIdx.x, b = blockIdx.x;
    int i0 = b * CHUNK + t * 4;
    int p[4];
#pragma unroll
    for (int j = 0; j < 4; ++j)
        p[j] = (i0 + j < N) ? ((counts[i0 + j] + 3) & ~3) : 0;
    int tsum = p[0] + p[1] + p[2] + p[3];
    sd[t] = tsum;
    __syncthreads();
    for (int d = 1; d < 256; d <<= 1) {
        int v = (t >= d) ? sd[t - d] : 0;
        __syncthreads();
        sd[t] += v;
        __syncthreads();
    }
    int pre = sd[t] - tsum;
#pragma unroll
    for (int j = 0; j < 4; ++j) {
        if (i0 + j < N) offs[i0 + j] = pre;
        pre += p[j];
    }
    if (t == 255) bsum[b] = sd[255];
}

// addoff with inline top-scan (nb <= 64)
__global__ __launch_bounds__(256) void k_addoff(int* __restrict__ offs,
                                                int* __restrict__ cursor,
                                                const int* __restrict__ bsum,
                                                int N, int nb) {
    __shared__ int base_s;
    int t = threadIdx.x;
    int i = blockIdx.x * 256 + t;
    int chunk = (blockIdx.x * 256) >> 10;
    if (t < 64) {
        int v = (t < chunk && t < nb) ? bsum[t] : 0;
#pragma unroll
        for (int off = 1; off < 64; off <<= 1) v += __shfl_xor(v, off);
        if (t == 0) base_s = v;
    }
    __syncthreads();
    if (i < N) {
        int o = offs[i] + base_s;
        offs[i] = o;
        cursor[i] = o;
    }
}

// ------------- scatter: 4 edges/thread, single 16B packed write each --------
__global__ __launch_bounds__(256) void k_scatter(const int* __restrict__ src,
                                                 const int* __restrict__ dst,
                                                 const float* __restrict__ ef,
                                                 const float* __restrict__ att,
                                                 const float* __restrict__ s_src,
                                                 const float* __restrict__ s_dst,
                                                 int* __restrict__ cursor,
                                                 int4* __restrict__ epack, int E) {
    int gid = blockIdx.x * 256 + threadIdx.x;
    int e0 = gid * 4;
    if (e0 >= E) return;
    float aE0 = att[64], aE1 = att[129], aE2 = att[194], aE3 = att[259];

    if (e0 + 3 < E) {
        int4 s4 = *reinterpret_cast<const int4*>(&src[e0]);
        int4 d4 = *reinterpret_cast<const int4*>(&dst[e0]);
        float4 f4 = *reinterpret_cast<const float4*>(&ef[e0]);
        // issue all gathers first (MLP)
        float4 ss0 = *reinterpret_cast<const float4*>(&s_src[(size_t)s4.x * 4]);
        float4 ss1 = *reinterpret_cast<const float4*>(&s_src[(size_t)s4.y * 4]);
        float4 ss2 = *reinterpret_cast<const float4*>(&s_src[(size_t)s4.z * 4]);
        float4 ss3 = *reinterpret_cast<const float4*>(&s_src[(size_t)s4.w * 4]);
        float4 sd0 = *reinterpret_cast<const float4*>(&s_dst[(size_t)d4.x * 4]);
        float4 sd1 = *reinterpret_cast<const float4*>(&s_dst[(size_t)d4.y * 4]);
        float4 sd2 = *reinterpret_cast<const float4*>(&s_dst[(size_t)d4.z * 4]);
        float4 sd3 = *reinterpret_cast<const float4*>(&s_dst[(size_t)d4.w * 4]);
        int p0 = atomicAdd(&cursor[d4.x], 1);
        int p1 = atomicAdd(&cursor[d4.y], 1);
        int p2 = atomicAdd(&cursor[d4.z], 1);
        int p3 = atomicAdd(&cursor[d4.w], 1);
#define EDGE(SS, SD, FV, SRCN, POS) { \
        float sc0 = SS.x + SD.x + FV * aE0; \
        float sc1 = SS.y + SD.y + FV * aE1; \
        float sc2 = SS.z + SD.z + FV * aE2; \
        float sc3 = SS.w + SD.w + FV * aE3; \
        sc0 = sc0 >= 0.f ? sc0 : 0.2f * sc0;  sc1 = sc1 >= 0.f ? sc1 : 0.2f * sc1; \
        sc2 = sc2 >= 0.f ? sc2 : 0.2f * sc2;  sc3 = sc3 >= 0.f ? sc3 : 0.2f * sc3; \
        float a0 = expf(fminf(fmaxf(sc0, -20.f), 20.f)); \
        float a1 = expf(fminf(fmaxf(sc1, -20.f), 20.f)); \
        float a2 = expf(fminf(fmaxf(sc2, -20.f), 20.f)); \
        float a3 = expf(fminf(fmaxf(sc3, -20.f), 20.f)); \
        epack[POS] = make_int4(SRCN, \
            (int)(((unsigned)f2bf(a1) << 16) | f2bf(a0)), \
            (int)(((unsigned)f2bf(a3) << 16) | f2bf(a2)), 0); }
        EDGE(ss0, sd0, f4.x, s4.x, p0)
        EDGE(ss1, sd1, f4.y, s4.y, p1)
        EDGE(ss2, sd2, f4.z, s4.z, p2)
        EDGE(ss3, sd3, f4.w, s4.w, p3)
    } else {
        for (int e = e0; e < E; ++e) {
            int s = src[e], d = dst[e];
            float fv = ef[e];
            float4 ss = *reinterpret_cast<const float4*>(&s_src[(size_t)s * 4]);
            float4 sd = *reinterpret_cast<const float4*>(&s_dst[(size_t)d * 4]);
            int pos = atomicAdd(&cursor[d], 1);
            EDGE(ss, sd, fv, s, pos)
        }
    }
#undef EDGE
}

// ------------- fused: aggregate + residual + LN + ELU -----------------------
// 2 nodes per wave: half-wave (32 lanes) per node, 4 channels per lane.
__global__ __launch_bounds__(256) void k_agg_final(const int* __restrict__ offs,
                                                   const int* __restrict__ counts,
                                                   const int4* __restrict__ epack,
                                                   const uint2* __restrict__ zb2,
                                                   const float* __restrict__ g,
                                                   const float* __restrict__ bparm,
                                                   float* __restrict__ out, int N) {
    int wave = threadIdx.x >> 6, lane = threadIdx.x & 63;
    int half = lane >> 5, l32 = lane & 31;
    int n = blockIdx.x * 8 + wave * 2 + half;
    if (n >= N) return;
    const int start = offs[n], len = counts[n];
    const int hd = l32 >> 3;
    float A0 = 0.f, A1 = 0.f, A2 = 0.f, A3 = 0.f, da = 0.f;
    float B0 = 0.f, B1 = 0.f, B2 = 0.f, B3 = 0.f, db = 0.f;
    int i = 0;
#define UNPK(P, AV) { unsigned u = (hd & 2) ? (unsigned)(P).z : (unsigned)(P).y; \
    AV = (hd & 1) ? bfH(u) : bfL(u); }
    for (; i + 3 < len; i += 4) {
        int4 p0 = epack[start + i + 0];
        int4 p1 = epack[start + i + 1];
        int4 p2 = epack[start + i + 2];
        int4 p3 = epack[start + i + 3];
        uint2 q0 = zb2[(size_t)p0.x * 32 + l32];
        uint2 q1 = zb2[(size_t)p1.x * 32 + l32];
        uint2 q2 = zb2[(size_t)p2.x * 32 + l32];
        uint2 q3 = zb2[(size_t)p3.x * 32 + l32];
        float a0, a1, a2, a3;
        UNPK(p0, a0) UNPK(p1, a1) UNPK(p2, a2) UNPK(p3, a3)
        A0 += bfL(q0.x) * a0; A1 += bfH(q0.x) * a0; A2 += bfL(q0.y) * a0; A3 += bfH(q0.y) * a0; da += a0;
        B0 += bfL(q1.x) * a1; B1 += bfH(q1.x) * a1; B2 += bfL(q1.y) * a1; B3 += bfH(q1.y) * a1; db += a1;
        A0 += bfL(q2.x) * a2; A1 += bfH(q2.x) * a2; A2 += bfL(q2.y) * a2; A3 += bfH(q2.y) * a2; da += a2;
        B0 += bfL(q3.x) * a3; B1 += bfH(q3.x) * a3; B2 += bfL(q3.y) * a3; B3 += bfH(q3.y) * a3; db += a3;
    }
    for (; i < len; ++i) {
        int4 p0 = epack[start + i];
        uint2 q0 = zb2[(size_t)p0.x * 32 + l32];
        float a0; UNPK(p0, a0)
        A0 += bfL(q0.x) * a0; A1 += bfH(q0.x) * a0; A2 += bfL(q0.y) * a0; A3 += bfH(q0.y) * a0; da += a0;
    }
#undef UNPK

    float inv = 1.f / (da + db + 1e-6f);
    uint2 qz = zb2[(size_t)n * 32 + l32];
    float x0 = (A0 + B0) * inv + bfL(qz.x);
    float x1 = (A1 + B1) * inv + bfH(qz.x);
    float x2 = (A2 + B2) * inv + bfL(qz.y);
    float x3 = (A3 + B3) * inv + bfH(qz.y);
    float s = x0 + x1 + x2 + x3;
#pragma unroll
    for (int off = 1; off < 32; off <<= 1) s += __shfl_xor(s, off);
    float mu = s * (1.f / 128.f);
    float d0 = x0 - mu, d1 = x1 - mu, d2 = x2 - mu, d3 = x3 - mu;
    float q = d0 * d0 + d1 * d1 + d2 * d2 + d3 * d3;
#pragma unroll
    for (int off = 1; off < 32; off <<= 1) q += __shfl_xor(q, off);
    float rstd = rsqrtf(q * (1.f / 128.f) + 1e-5f);
    float4 gg = *reinterpret_cast<const float4*>(&g[l32 * 4]);
    float4 bb = *reinterpret_cast<const float4*>(&bparm[l32 * 4]);
    float y0 = d0 * rstd * gg.x + bb.x;
    float y1 = d1 * rstd * gg.y + bb.y;
    float y2 = d2 * rstd * gg.z + bb.z;
    float y3 = d3 * rstd * gg.w + bb.w;
    y0 = y0 > 0.f ? y0 : expf(y0) - 1.f;
    y1 = y1 > 0.f ? y1 : expf(y1) - 1.f;
    y2 = y2 > 0.f ? y2 : expf(y2) - 1.f;
    y3 = y3 > 0.f ? y3 : expf(y3) - 1.f;
    *reinterpret_cast<float4*>(&out[(size_t)n * 128 + l32 * 4]) =
        make_float4(y0, y1, y2, y3);
}

extern "C" void kernel_launch(void* const* d_in, const int* in_sizes, int n_in,
                              void* d_out, int out_size, void* d_ws, size_t ws_size,
                              hipStream_t stream) {
    const float* h   = (const float*)d_in[0];
    const int*   ei  = (const int*)d_in[1];
    const float* ef  = (const float*)d_in[2];
    const float* Ww  = (const float*)d_in[3];
    const float* Wb  = (const float*)d_in[4];
    const float* att = (const float*)d_in[5];
    const float* lng = (const float*)d_in[6];
    const float* lnb = (const float*)d_in[7];
    float* out = (float*)d_out;

    const int N = in_sizes[0] / 128;   // 50000
    const int E = in_sizes[1] / 2;     // 800000
    const int* src = ei;
    const int* dst = ei + E;
    const int nb = (N + CHUNK - 1) / CHUNK;   // 49 (<=64 required)
    const int sortedCap = E + 3 * N + 64;

    char* ws = (char*)d_ws;
    unsigned short* zb16     = (unsigned short*)ws; ws += (size_t)N * 128 * 2;
    unsigned short* Wb16     = (unsigned short*)ws; ws += (size_t)128 * 128 * 2;
    unsigned short* wsdB     = (unsigned short*)ws; ws += (size_t)16 * 16 * 8 * 2;
    float*          consts   = (float*)ws;          ws += (size_t)8 * 4;
    float*          s_src    = (float*)ws;          ws += (size_t)N * 4 * 4;
    float*          s_dst    = (float*)ws;          ws += (size_t)N * 4 * 4;
    int*            counts   = (int*)ws;            ws += (size_t)N * 4;
    int*            offs     = (int*)ws;            ws += (size_t)N * 4;
    int*            cursor   = (int*)ws;            ws += (size_t)N * 4;
    int*            bsum     = (int*)ws;            ws += (size_t)64 * 4;
    int4*           epack    = (int4*)ws;           ws += (size_t)sortedCap * 16;

    const int zeroBlocks = (N + 1023) / 1024;        // 49
    k_prep<<<2 + zeroBlocks, 256, 0, stream>>>(Ww, Wb, att, Wb16, wsdB, consts, counts, N);

    const int gemmBlocks = (N + 63) / 64;            // 782
    const int histBlocks = (E + 1023) / 1024;        // 782
    k_mega<<<gemmBlocks + histBlocks, 256, 0, stream>>>(
        h, Wb16, wsdB, consts, Wb, dst, counts, zb16, s_src, s_dst, N, E, gemmBlocks);
    k_scan_block<<<nb, 256, 0, stream>>>(counts, offs, bsum, N);
    k_addoff<<<(N + 255) / 256, 256, 0, stream>>>(offs, cursor, bsum, N, nb);
    k_scatter<<<(E / 4 + 255) / 256, 256, 0, stream>>>(src, dst, ef, att, s_src, s_dst, cursor, epack, E);
    k_agg_final<<<(N + 7) / 8, 256, 0, stream>>>(offs, counts, epack,
                                                 (const uint2*)zb16, lng, lnb, out, N);
}

// Round 11
// 144.740 us; speedup vs baseline: 1.1311x; 1.1011x over previous
//
#include <hip/hip_runtime.h>
#include <hip/hip_bf16.h>
#include <math.h>

typedef __attribute__((ext_vector_type(8))) short bf16x8;
typedef __attribute__((ext_vector_type(4))) float f32x4;

__device__ __forceinline__ unsigned short f2bf(float f) {
    unsigned u = __float_as_uint(f);
    unsigned r = ((u >> 16) & 1u) + 0x7fffu;   // RNE
    return (unsigned short)((u + r) >> 16);
}
__device__ __forceinline__ float bf2f(unsigned short s) {
    return __uint_as_float((unsigned)s << 16);
}
__device__ __forceinline__ float bfL(unsigned u) { return __uint_as_float(u << 16); }
__device__ __forceinline__ float bfH(unsigned u) { return __uint_as_float(u & 0xffff0000u); }

// ---- prep ------------------------------------------------------------------
// block 0: W -> bf16 MFMA fragment order (granule gi = kg*128 + row;
//          k = (kg>>2)*32 + (e>>2)*16 + (kg&3)*4 + (e&3))
// block 1: score matrix wsdB (16 comps x 128 k, bf16 hi/lo split) + consts
__global__ __launch_bounds__(256) void k_prep(const float* __restrict__ W,
                                              const float* __restrict__ bias,
                                              const float* __restrict__ att,
                                              unsigned short* __restrict__ Wb16,
                                              unsigned short* __restrict__ wsdB,
                                              float* __restrict__ consts) {
    const int t = threadIdx.x;
    if (blockIdx.x == 0) {
#pragma unroll
        for (int q = 0; q < 8; ++q) {
            int gi = q * 256 + t;
            int kg = gi >> 7, row = gi & 127;
            int kbase = (kg >> 2) * 32 + (kg & 3) * 4;
            unsigned pk[4];
#pragma unroll
            for (int p = 0; p < 4; ++p) {
                int e0 = 2 * p, e1 = 2 * p + 1;
                float v0 = W[(size_t)row * 128 + kbase + (e0 >> 2) * 16 + (e0 & 3)];
                float v1 = W[(size_t)row * 128 + kbase + (e1 >> 2) * 16 + (e1 & 3)];
                pk[p] = ((unsigned)f2bf(v1) << 16) | f2bf(v0);
            }
            *reinterpret_cast<uint4*>(&Wb16[(size_t)gi * 8]) =
                make_uint4(pk[0], pk[1], pk[2], pk[3]);
        }
    } else {
        int kg = t >> 4, la = t & 15;
        int hd = la & 3;
        int isDst = (la >> 2) & 1;
        int isLo = la >> 3;
        unsigned short vals[8];
#pragma unroll
        for (int e = 0; e < 8; ++e) {
            int k = (kg >> 2) * 32 + (e >> 2) * 16 + (kg & 3) * 4 + (e & 3);
            float w = 0.f;
            for (int j = 0; j < 32; ++j)
                w += W[(size_t)(hd * 32 + j) * 128 + k] * att[hd * 65 + isDst * 32 + j];
            unsigned short hi = f2bf(w);
            vals[e] = isLo ? f2bf(w - bf2f(hi)) : hi;
        }
        int gi = kg * 16 + la;
        unsigned pk[4];
#pragma unroll
        for (int p = 0; p < 4; ++p)
            pk[p] = ((unsigned)vals[2 * p + 1] << 16) | vals[2 * p];
        *reinterpret_cast<uint4*>(&wsdB[(size_t)gi * 8]) =
            make_uint4(pk[0], pk[1], pk[2], pk[3]);
        if (t < 8) {
            int chd = t & 3, cIsD = t >> 2;
            float c = 0.f;
            for (int j = 0; j < 32; ++j)
                c += bias[chd * 32 + j] * att[chd * 65 + cIsD * 32 + j];
            consts[t] = c;
        }
    }
}

// ---- mega: MFMA GEMM (swapped operands: D[col][node]) + scores -------------
// grid = 2 * ceil(N/64); bid&1 selects column half (64 cols) -> 6 blocks/CU.
__global__ __launch_bounds__(256) void k_mega(
        const float* __restrict__ h, const unsigned short* __restrict__ Wb16,
        const unsigned short* __restrict__ wsdB, const float* __restrict__ consts,
        const float* __restrict__ bias,
        unsigned short* __restrict__ zb16,
        float* __restrict__ s_src, float* __restrict__ s_dst, int N) {
    __shared__ short hS[16 * 64 * 8];    // 16 KB
    const int t = threadIdx.x;
    const int by = blockIdx.x & 1;
    const int n0 = (blockIdx.x >> 1) * 64;
    const int obase = by * 64;

#pragma unroll
    for (int q = 0; q < 8; ++q) {
        int f = q * 256 + t;
        int nd = f >> 5;
        int k4 = (f & 31) * 4;
        int ks = k4 >> 5, rr = k4 & 31;
        int half = rr >> 4, g = (rr & 15) >> 2;
        int kg = ks * 4 + g;
        int slot = kg * 64 + (nd ^ (kg & 7));
        int hn = n0 + nd; if (hn > N - 1) hn = N - 1;
        float4 v = *reinterpret_cast<const float4*>(&h[(size_t)hn * 128 + k4]);
        uint2 pk = make_uint2(((unsigned)f2bf(v.y) << 16) | f2bf(v.x),
                              ((unsigned)f2bf(v.w) << 16) | f2bf(v.z));
        *reinterpret_cast<uint2*>(&hS[slot * 8 + half * 4]) = pk;
    }
    __syncthreads();

    const int wv = t >> 6, l = t & 63;
    const int la = l & 15, lb = l >> 4;
    const int nbase = wv * 16;
    const int node = n0 + nbase + la;

    bf16x8 hfr[4];
#pragma unroll
    for (int ks = 0; ks < 4; ++ks) {
        int kg = ks * 4 + lb;
        int slot = kg * 64 + ((nbase + la) ^ (kg & 7));
        hfr[ks] = *reinterpret_cast<const bf16x8*>(&hS[slot * 8]);
    }

    if (by == 0) {
        // scores: A = wsdB (16 comps), B = h  ->  D[comp][node]
        f32x4 accS = {0.f, 0.f, 0.f, 0.f};
#pragma unroll
        for (int ks = 0; ks < 4; ++ks) {
            int kg = ks * 4 + lb;
            bf16x8 sfr = *reinterpret_cast<const bf16x8*>(&wsdB[(size_t)(kg * 16 + la) * 8]);
            accS = __builtin_amdgcn_mfma_f32_16x16x32_bf16(sfr, hfr[ks], accS, 0, 0, 0);
        }
        float t0 = accS[0] + __shfl_xor(accS[0], 32);   // hi + lo (lb 0<->2, 1<->3)
        float t1 = accS[1] + __shfl_xor(accS[1], 32);
        float t2 = accS[2] + __shfl_xor(accS[2], 32);
        float t3 = accS[3] + __shfl_xor(accS[3], 32);
        if (lb < 2 && node < N) {
            float4 cv = *reinterpret_cast<const float4*>(&consts[lb * 4]);
            float4 o = make_float4(t0 + cv.x, t1 + cv.y, t2 + cv.z, t3 + cv.w);
            float* dp = (lb == 0) ? s_src : s_dst;
            *reinterpret_cast<float4*>(&dp[(size_t)node * 4]) = o;
        }
    }

    // GEMM over this block's column half
#pragma unroll
    for (int ot = 0; ot < 4; ++ot) {
        f32x4 acc = {0.f, 0.f, 0.f, 0.f};
#pragma unroll
        for (int ks = 0; ks < 4; ++ks) {
            int kg = ks * 4 + lb;
            bf16x8 wfr = *reinterpret_cast<const bf16x8*>(
                &Wb16[((size_t)kg * 128 + obase + ot * 16 + la) * 8]);
            acc = __builtin_amdgcn_mfma_f32_16x16x32_bf16(wfr, hfr[ks], acc, 0, 0, 0);
        }
        int colb = obase + ot * 16 + lb * 4;
        float4 bq = *reinterpret_cast<const float4*>(&bias[colb]);
        if (node < N) {
            uint2 pk = make_uint2(
                ((unsigned)f2bf(acc[1] + bq.y) << 16) | f2bf(acc[0] + bq.x),
                ((unsigned)f2bf(acc[3] + bq.w) << 16) | f2bf(acc[2] + bq.z));
            *reinterpret_cast<uint2*>(&zb16[(size_t)node * 128 + colb]) = pk;
        }
    }
}

// ---- edge: alpha (dense) + linked-list build (2 chains per dst node) -------
__global__ __launch_bounds__(256) void k_edge(const int* __restrict__ src,
                                              const int* __restrict__ dst,
                                              const float* __restrict__ ef,
                                              const float* __restrict__ att,
                                              const float* __restrict__ s_src,
                                              const float* __restrict__ s_dst,
                                              int* __restrict__ head2,
                                              int4* __restrict__ epkt, int E) {
    int e = blockIdx.x * 256 + threadIdx.x;
    if (e >= E) return;
    int s = src[e], d = dst[e];
    float fv = ef[e];
    float4 ss = *reinterpret_cast<const float4*>(&s_src[(size_t)s * 4]);
    float4 sd = *reinterpret_cast<const float4*>(&s_dst[(size_t)d * 4]);
    float aE0 = att[64], aE1 = att[129], aE2 = att[194], aE3 = att[259];
    float sc0 = ss.x + sd.x + fv * aE0;
    float sc1 = ss.y + sd.y + fv * aE1;
    float sc2 = ss.z + sd.z + fv * aE2;
    float sc3 = ss.w + sd.w + fv * aE3;
    sc0 = sc0 >= 0.f ? sc0 : 0.2f * sc0;  sc1 = sc1 >= 0.f ? sc1 : 0.2f * sc1;
    sc2 = sc2 >= 0.f ? sc2 : 0.2f * sc2;  sc3 = sc3 >= 0.f ? sc3 : 0.2f * sc3;
    float a0 = expf(fminf(fmaxf(sc0, -20.f), 20.f));
    float a1 = expf(fminf(fmaxf(sc1, -20.f), 20.f));
    float a2 = expf(fminf(fmaxf(sc2, -20.f), 20.f));
    float a3 = expf(fminf(fmaxf(sc3, -20.f), 20.f));
    int prev = atomicExch(&head2[(size_t)d * 2 + (e & 1)], e);
    epkt[e] = make_int4(s, prev,
        (int)(((unsigned)f2bf(a1) << 16) | f2bf(a0)),
        (int)(((unsigned)f2bf(a3) << 16) | f2bf(a2)));
}

// ---- fused: chain-walk aggregate + residual + LN + ELU ---------------------
// 2 nodes per wave (32 lanes/node, 4 channels/lane); 2 chains per node.
__global__ __launch_bounds__(256) void k_agg_final(const int* __restrict__ head2,
                                                   const int4* __restrict__ epkt,
                                                   const uint2* __restrict__ zb2,
                                                   const float* __restrict__ g,
                                                   const float* __restrict__ bparm,
                                                   float* __restrict__ out, int N) {
    int wave = threadIdx.x >> 6, lane = threadIdx.x & 63;
    int half = lane >> 5, l32 = lane & 31;
    int n = blockIdx.x * 8 + wave * 2 + half;
    if (n >= N) return;
    const int hd = l32 >> 3;
    int e0 = head2[(size_t)n * 2 + 0];
    int e1 = head2[(size_t)n * 2 + 1];
    float A0 = 0.f, A1 = 0.f, A2 = 0.f, A3 = 0.f, da = 0.f;
    float B0 = 0.f, B1 = 0.f, B2 = 0.f, B3 = 0.f, db = 0.f;
#define UNPK(P, AV) { unsigned u = (hd & 2) ? (unsigned)(P).w : (unsigned)(P).z; \
    AV = (hd & 1) ? bfH(u) : bfL(u); }
    while (e0 != -1 || e1 != -1) {
        if (e0 != -1) {
            int4 p = epkt[e0];
            uint2 q = zb2[(size_t)p.x * 32 + l32];
            float a; UNPK(p, a)
            A0 += bfL(q.x) * a; A1 += bfH(q.x) * a;
            A2 += bfL(q.y) * a; A3 += bfH(q.y) * a; da += a;
            e0 = p.y;
        }
        if (e1 != -1) {
            int4 p = epkt[e1];
            uint2 q = zb2[(size_t)p.x * 32 + l32];
            float a; UNPK(p, a)
            B0 += bfL(q.x) * a; B1 += bfH(q.x) * a;
            B2 += bfL(q.y) * a; B3 += bfH(q.y) * a; db += a;
            e1 = p.y;
        }
    }
#undef UNPK

    float inv = 1.f / (da + db + 1e-6f);
    uint2 qz = zb2[(size_t)n * 32 + l32];
    float x0 = (A0 + B0) * inv + bfL(qz.x);
    float x1 = (A1 + B1) * inv + bfH(qz.x);
    float x2 = (A2 + B2) * inv + bfL(qz.y);
    float x3 = (A3 + B3) * inv + bfH(qz.y);
    float s = x0 + x1 + x2 + x3;
#pragma unroll
    for (int off = 1; off < 32; off <<= 1) s += __shfl_xor(s, off);
    float mu = s * (1.f / 128.f);
    float d0 = x0 - mu, d1 = x1 - mu, d2 = x2 - mu, d3 = x3 - mu;
    float q = d0 * d0 + d1 * d1 + d2 * d2 + d3 * d3;
#pragma unroll
    for (int off = 1; off < 32; off <<= 1) q += __shfl_xor(q, off);
    float rstd = rsqrtf(q * (1.f / 128.f) + 1e-5f);
    float4 gg = *reinterpret_cast<const float4*>(&g[l32 * 4]);
    float4 bb = *reinterpret_cast<const float4*>(&bparm[l32 * 4]);
    float y0 = d0 * rstd * gg.x + bb.x;
    float y1 = d1 * rstd * gg.y + bb.y;
    float y2 = d2 * rstd * gg.z + bb.z;
    float y3 = d3 * rstd * gg.w + bb.w;
    y0 = y0 > 0.f ? y0 : expf(y0) - 1.f;
    y1 = y1 > 0.f ? y1 : expf(y1) - 1.f;
    y2 = y2 > 0.f ? y2 : expf(y2) - 1.f;
    y3 = y3 > 0.f ? y3 : expf(y3) - 1.f;
    *reinterpret_cast<float4*>(&out[(size_t)n * 128 + l32 * 4]) =
        make_float4(y0, y1, y2, y3);
}

extern "C" void kernel_launch(void* const* d_in, const int* in_sizes, int n_in,
                              void* d_out, int out_size, void* d_ws, size_t ws_size,
                              hipStream_t stream) {
    const float* h   = (const float*)d_in[0];
    const int*   ei  = (const int*)d_in[1];
    const float* ef  = (const float*)d_in[2];
    const float* Ww  = (const float*)d_in[3];
    const float* Wb  = (const float*)d_in[4];
    const float* att = (const float*)d_in[5];
    const float* lng = (const float*)d_in[6];
    const float* lnb = (const float*)d_in[7];
    float* out = (float*)d_out;

    const int N = in_sizes[0] / 128;   // 50000
    const int E = in_sizes[1] / 2;     // 800000
    const int* src = ei;
    const int* dst = ei + E;

    char* ws = (char*)d_ws;
    unsigned short* zb16   = (unsigned short*)ws; ws += (size_t)N * 128 * 2;
    unsigned short* Wb16   = (unsigned short*)ws; ws += (size_t)128 * 128 * 2;
    unsigned short* wsdB   = (unsigned short*)ws; ws += (size_t)16 * 16 * 8 * 2;
    float*          consts = (float*)ws;          ws += (size_t)8 * 4;
    float*          s_src  = (float*)ws;          ws += (size_t)N * 4 * 4;
    float*          s_dst  = (float*)ws;          ws += (size_t)N * 4 * 4;
    int*            head2  = (int*)ws;            ws += (size_t)N * 2 * 4;
    int4*           epkt   = (int4*)ws;           ws += (size_t)E * 16;

    hipMemsetAsync(head2, 0xFF, (size_t)N * 2 * 4, stream);   // all -1
    k_prep<<<2, 256, 0, stream>>>(Ww, Wb, att, Wb16, wsdB, consts);

    const int gemmBlocks = ((N + 63) / 64) * 2;   // 1564
    k_mega<<<gemmBlocks, 256, 0, stream>>>(
        h, Wb16, wsdB, consts, Wb, zb16, s_src, s_dst, N);
    k_edge<<<(E + 255) / 256, 256, 0, stream>>>(src, dst, ef, att, s_src, s_dst,
                                                head2, epkt, E);
    k_agg_final<<<(N + 7) / 8, 256, 0, stream>>>(head2, epkt,
                                                 (const uint2*)zb16, lng, lnb, out, N);
}

// Round 12
// 128.311 us; speedup vs baseline: 1.2759x; 1.1280x over previous
//
#include <hip/hip_runtime.h>
#include <hip/hip_bf16.h>
#include <math.h>

typedef __attribute__((ext_vector_type(8))) short bf16x8;
typedef __attribute__((ext_vector_type(4))) float f32x4;

__device__ __forceinline__ unsigned short f2bf(float f) {
    unsigned u = __float_as_uint(f);
    unsigned r = ((u >> 16) & 1u) + 0x7fffu;   // RNE
    return (unsigned short)((u + r) >> 16);
}
__device__ __forceinline__ float bf2f(unsigned short s) {
    return __uint_as_float((unsigned)s << 16);
}
__device__ __forceinline__ float bfL(unsigned u) { return __uint_as_float(u << 16); }
__device__ __forceinline__ float bfH(unsigned u) { return __uint_as_float(u & 0xffff0000u); }

// ---- prep ------------------------------------------------------------------
// block 0: W -> bf16 MFMA fragment order; block 1: score matrix + consts;
// blocks 2+: head4 = -1
__global__ __launch_bounds__(256) void k_prep(const float* __restrict__ W,
                                              const float* __restrict__ bias,
                                              const float* __restrict__ att,
                                              unsigned short* __restrict__ Wb16,
                                              unsigned short* __restrict__ wsdB,
                                              float* __restrict__ consts,
                                              int* __restrict__ head4, int N) {
    const int t = threadIdx.x;
    const int bid = blockIdx.x;
    if (bid == 0) {
#pragma unroll
        for (int q = 0; q < 8; ++q) {
            int gi = q * 256 + t;
            int kg = gi >> 7, row = gi & 127;
            int kbase = (kg >> 2) * 32 + (kg & 3) * 4;
            unsigned pk[4];
#pragma unroll
            for (int p = 0; p < 4; ++p) {
                int e0 = 2 * p, e1 = 2 * p + 1;
                float v0 = W[(size_t)row * 128 + kbase + (e0 >> 2) * 16 + (e0 & 3)];
                float v1 = W[(size_t)row * 128 + kbase + (e1 >> 2) * 16 + (e1 & 3)];
                pk[p] = ((unsigned)f2bf(v1) << 16) | f2bf(v0);
            }
            *reinterpret_cast<uint4*>(&Wb16[(size_t)gi * 8]) =
                make_uint4(pk[0], pk[1], pk[2], pk[3]);
        }
    } else if (bid == 1) {
        int kg = t >> 4, la = t & 15;
        int hd = la & 3;
        int isDst = (la >> 2) & 1;
        int isLo = la >> 3;
        unsigned short vals[8];
#pragma unroll
        for (int e = 0; e < 8; ++e) {
            int k = (kg >> 2) * 32 + (e >> 2) * 16 + (kg & 3) * 4 + (e & 3);
            float w = 0.f;
            for (int j = 0; j < 32; ++j)
                w += W[(size_t)(hd * 32 + j) * 128 + k] * att[hd * 65 + isDst * 32 + j];
            unsigned short hi = f2bf(w);
            vals[e] = isLo ? f2bf(w - bf2f(hi)) : hi;
        }
        int gi = kg * 16 + la;
        unsigned pk[4];
#pragma unroll
        for (int p = 0; p < 4; ++p)
            pk[p] = ((unsigned)vals[2 * p + 1] << 16) | vals[2 * p];
        *reinterpret_cast<uint4*>(&wsdB[(size_t)gi * 8]) =
            make_uint4(pk[0], pk[1], pk[2], pk[3]);
        if (t < 8) {
            int chd = t & 3, cIsD = t >> 2;
            float c = 0.f;
            for (int j = 0; j < 32; ++j)
                c += bias[chd * 32 + j] * att[chd * 65 + cIsD * 32 + j];
            consts[t] = c;
        }
    } else {
        int i = ((bid - 2) * 256 + t) * 4;
        if (i < N * 4)
            *reinterpret_cast<int4*>(&head4[i]) = make_int4(-1, -1, -1, -1);
    }
}

// ---- mega: MFMA GEMM (swapped operands: D[col][node]) + scores -------------
__global__ __launch_bounds__(256) void k_mega(
        const float* __restrict__ h, const unsigned short* __restrict__ Wb16,
        const unsigned short* __restrict__ wsdB, const float* __restrict__ consts,
        const float* __restrict__ bias,
        unsigned short* __restrict__ zb16,
        float* __restrict__ s_src, float* __restrict__ s_dst, int N) {
    __shared__ short hS[16 * 64 * 8];    // 16 KB
    const int t = threadIdx.x;
    const int by = blockIdx.x & 1;
    const int n0 = (blockIdx.x >> 1) * 64;
    const int obase = by * 64;

#pragma unroll
    for (int q = 0; q < 8; ++q) {
        int f = q * 256 + t;
        int nd = f >> 5;
        int k4 = (f & 31) * 4;
        int ks = k4 >> 5, rr = k4 & 31;
        int half = rr >> 4, g = (rr & 15) >> 2;
        int kg = ks * 4 + g;
        int slot = kg * 64 + (nd ^ (kg & 7));
        int hn = n0 + nd; if (hn > N - 1) hn = N - 1;
        float4 v = *reinterpret_cast<const float4*>(&h[(size_t)hn * 128 + k4]);
        uint2 pk = make_uint2(((unsigned)f2bf(v.y) << 16) | f2bf(v.x),
                              ((unsigned)f2bf(v.w) << 16) | f2bf(v.z));
        *reinterpret_cast<uint2*>(&hS[slot * 8 + half * 4]) = pk;
    }
    __syncthreads();

    const int wv = t >> 6, l = t & 63;
    const int la = l & 15, lb = l >> 4;
    const int nbase = wv * 16;
    const int node = n0 + nbase + la;

    bf16x8 hfr[4];
#pragma unroll
    for (int ks = 0; ks < 4; ++ks) {
        int kg = ks * 4 + lb;
        int slot = kg * 64 + ((nbase + la) ^ (kg & 7));
        hfr[ks] = *reinterpret_cast<const bf16x8*>(&hS[slot * 8]);
    }

    if (by == 0) {
        f32x4 accS = {0.f, 0.f, 0.f, 0.f};
#pragma unroll
        for (int ks = 0; ks < 4; ++ks) {
            int kg = ks * 4 + lb;
            bf16x8 sfr = *reinterpret_cast<const bf16x8*>(&wsdB[(size_t)(kg * 16 + la) * 8]);
            accS = __builtin_amdgcn_mfma_f32_16x16x32_bf16(sfr, hfr[ks], accS, 0, 0, 0);
        }
        float t0 = accS[0] + __shfl_xor(accS[0], 32);
        float t1 = accS[1] + __shfl_xor(accS[1], 32);
        float t2 = accS[2] + __shfl_xor(accS[2], 32);
        float t3 = accS[3] + __shfl_xor(accS[3], 32);
        if (lb < 2 && node < N) {
            float4 cv = *reinterpret_cast<const float4*>(&consts[lb * 4]);
            float4 o = make_float4(t0 + cv.x, t1 + cv.y, t2 + cv.z, t3 + cv.w);
            float* dp = (lb == 0) ? s_src : s_dst;
            *reinterpret_cast<float4*>(&dp[(size_t)node * 4]) = o;
        }
    }

#pragma unroll
    for (int ot = 0; ot < 4; ++ot) {
        f32x4 acc = {0.f, 0.f, 0.f, 0.f};
#pragma unroll
        for (int ks = 0; ks < 4; ++ks) {
            int kg = ks * 4 + lb;
            bf16x8 wfr = *reinterpret_cast<const bf16x8*>(
                &Wb16[((size_t)kg * 128 + obase + ot * 16 + la) * 8]);
            acc = __builtin_amdgcn_mfma_f32_16x16x32_bf16(wfr, hfr[ks], acc, 0, 0, 0);
        }
        int colb = obase + ot * 16 + lb * 4;
        float4 bq = *reinterpret_cast<const float4*>(&bias[colb]);
        if (node < N) {
            uint2 pk = make_uint2(
                ((unsigned)f2bf(acc[1] + bq.y) << 16) | f2bf(acc[0] + bq.x),
                ((unsigned)f2bf(acc[3] + bq.w) << 16) | f2bf(acc[2] + bq.z));
            *reinterpret_cast<uint2*>(&zb16[(size_t)node * 128 + colb]) = pk;
        }
    }
}

// ---- edge: alpha (dense) + linked-list build (4 chains per dst node) -------
__global__ __launch_bounds__(256) void k_edge(const int* __restrict__ src,
                                              const int* __restrict__ dst,
                                              const float* __restrict__ ef,
                                              const float* __restrict__ att,
                                              const float* __restrict__ s_src,
                                              const float* __restrict__ s_dst,
                                              int* __restrict__ head4,
                                              int4* __restrict__ epkt, int E) {
    int e = blockIdx.x * 256 + threadIdx.x;
    if (e >= E) return;
    int s = src[e], d = dst[e];
    float fv = ef[e];
    float4 ss = *reinterpret_cast<const float4*>(&s_src[(size_t)s * 4]);
    float4 sd = *reinterpret_cast<const float4*>(&s_dst[(size_t)d * 4]);
    float aE0 = att[64], aE1 = att[129], aE2 = att[194], aE3 = att[259];
    float sc0 = ss.x + sd.x + fv * aE0;
    float sc1 = ss.y + sd.y + fv * aE1;
    float sc2 = ss.z + sd.z + fv * aE2;
    float sc3 = ss.w + sd.w + fv * aE3;
    sc0 = sc0 >= 0.f ? sc0 : 0.2f * sc0;  sc1 = sc1 >= 0.f ? sc1 : 0.2f * sc1;
    sc2 = sc2 >= 0.f ? sc2 : 0.2f * sc2;  sc3 = sc3 >= 0.f ? sc3 : 0.2f * sc3;
    float a0 = expf(fminf(fmaxf(sc0, -20.f), 20.f));
    float a1 = expf(fminf(fmaxf(sc1, -20.f), 20.f));
    float a2 = expf(fminf(fmaxf(sc2, -20.f), 20.f));
    float a3 = expf(fminf(fmaxf(sc3, -20.f), 20.f));
    int prev = atomicExch(&head4[(size_t)d * 4 + (e & 3)], e);
    epkt[e] = make_int4(s, prev,
        (int)(((unsigned)f2bf(a1) << 16) | f2bf(a0)),
        (int)(((unsigned)f2bf(a3) << 16) | f2bf(a2)));
}

// ---- fused: 4-chain walk aggregate + residual + LN + ELU -------------------
// 4 nodes per wave (16 lanes/node, 8 channels/lane); 4 chains per node.
__global__ __launch_bounds__(256) void k_agg_final(const int* __restrict__ head4,
                                                   const int4* __restrict__ epkt,
                                                   const uint4* __restrict__ zb4,
                                                   const float* __restrict__ g,
                                                   const float* __restrict__ bparm,
                                                   float* __restrict__ out, int N) {
    int wave = threadIdx.x >> 6, lane = threadIdx.x & 63;
    int l16 = lane & 15;
    int n = blockIdx.x * 16 + wave * 4 + (lane >> 4);
    if (n >= N) return;
    const int hd = l16 >> 2;            // head of channels l16*8..+7
    int4 eh = *reinterpret_cast<const int4*>(&head4[(size_t)n * 4]);
    int e0 = eh.x, e1 = eh.y, e2 = eh.z, e3 = eh.w;
    float A0 = 0.f, A1 = 0.f, A2 = 0.f, A3 = 0.f;
    float A4 = 0.f, A5 = 0.f, A6 = 0.f, A7 = 0.f;
    float da = 0.f;
#define UNPK(P, AV) { unsigned u = (hd & 2) ? (unsigned)(P).w : (unsigned)(P).z; \
    AV = (hd & 1) ? bfH(u) : bfL(u); }
#define STEP(EV) if (EV != -1) { \
        int4 p = epkt[EV]; \
        uint4 q = zb4[(size_t)p.x * 16 + l16]; \
        float a; UNPK(p, a) \
        A0 += bfL(q.x) * a; A1 += bfH(q.x) * a; \
        A2 += bfL(q.y) * a; A3 += bfH(q.y) * a; \
        A4 += bfL(q.z) * a; A5 += bfH(q.z) * a; \
        A6 += bfL(q.w) * a; A7 += bfH(q.w) * a; \
        da += a; EV = p.y; }
    while (((e0 & e1) & (e2 & e3)) != -1) {
        STEP(e0) STEP(e1) STEP(e2) STEP(e3)
    }
#undef STEP
#undef UNPK

    float inv = 1.f / (da + 1e-6f);
    uint4 qz = zb4[(size_t)n * 16 + l16];
    float x0 = A0 * inv + bfL(qz.x);
    float x1 = A1 * inv + bfH(qz.x);
    float x2 = A2 * inv + bfL(qz.y);
    float x3 = A3 * inv + bfH(qz.y);
    float x4 = A4 * inv + bfL(qz.z);
    float x5 = A5 * inv + bfH(qz.z);
    float x6 = A6 * inv + bfL(qz.w);
    float x7 = A7 * inv + bfH(qz.w);
    float s = ((x0 + x1) + (x2 + x3)) + ((x4 + x5) + (x6 + x7));
#pragma unroll
    for (int off = 1; off < 16; off <<= 1) s += __shfl_xor(s, off);
    float mu = s * (1.f / 128.f);
    float d0 = x0 - mu, d1 = x1 - mu, d2 = x2 - mu, d3 = x3 - mu;
    float d4 = x4 - mu, d5 = x5 - mu, d6 = x6 - mu, d7 = x7 - mu;
    float q = ((d0 * d0 + d1 * d1) + (d2 * d2 + d3 * d3))
            + ((d4 * d4 + d5 * d5) + (d6 * d6 + d7 * d7));
#pragma unroll
    for (int off = 1; off < 16; off <<= 1) q += __shfl_xor(q, off);
    float rstd = rsqrtf(q * (1.f / 128.f) + 1e-5f);
    const int c = l16 * 8;
    float4 g0 = *reinterpret_cast<const float4*>(&g[c]);
    float4 g1 = *reinterpret_cast<const float4*>(&g[c + 4]);
    float4 b0 = *reinterpret_cast<const float4*>(&bparm[c]);
    float4 b1 = *reinterpret_cast<const float4*>(&bparm[c + 4]);
    float y0 = d0 * rstd * g0.x + b0.x;
    float y1 = d1 * rstd * g0.y + b0.y;
    float y2 = d2 * rstd * g0.z + b0.z;
    float y3 = d3 * rstd * g0.w + b0.w;
    float y4 = d4 * rstd * g1.x + b1.x;
    float y5 = d5 * rstd * g1.y + b1.y;
    float y6 = d6 * rstd * g1.z + b1.z;
    float y7 = d7 * rstd * g1.w + b1.w;
    y0 = y0 > 0.f ? y0 : expf(y0) - 1.f;
    y1 = y1 > 0.f ? y1 : expf(y1) - 1.f;
    y2 = y2 > 0.f ? y2 : expf(y2) - 1.f;
    y3 = y3 > 0.f ? y3 : expf(y3) - 1.f;
    y4 = y4 > 0.f ? y4 : expf(y4) - 1.f;
    y5 = y5 > 0.f ? y5 : expf(y5) - 1.f;
    y6 = y6 > 0.f ? y6 : expf(y6) - 1.f;
    y7 = y7 > 0.f ? y7 : expf(y7) - 1.f;
    *reinterpret_cast<float4*>(&out[(size_t)n * 128 + c]) = make_float4(y0, y1, y2, y3);
    *reinterpret_cast<float4*>(&out[(size_t)n * 128 + c + 4]) = make_float4(y4, y5, y6, y7);
}

extern "C" void kernel_launch(void* const* d_in, const int* in_sizes, int n_in,
                              void* d_out, int out_size, void* d_ws, size_t ws_size,
                              hipStream_t stream) {
    const float* h   = (const float*)d_in[0];
    const int*   ei  = (const int*)d_in[1];
    const float* ef  = (const float*)d_in[2];
    const float* Ww  = (const float*)d_in[3];
    const float* Wb  = (const float*)d_in[4];
    const float* att = (const float*)d_in[5];
    const float* lng = (const float*)d_in[6];
    const float* lnb = (const float*)d_in[7];
    float* out = (float*)d_out;

    const int N = in_sizes[0] / 128;   // 50000
    const int E = in_sizes[1] / 2;     // 800000
    const int* src = ei;
    const int* dst = ei + E;

    char* ws = (char*)d_ws;
    unsigned short* zb16   = (unsigned short*)ws; ws += (size_t)N * 128 * 2;
    unsigned short* Wb16   = (unsigned short*)ws; ws += (size_t)128 * 128 * 2;
    unsigned short* wsdB   = (unsigned short*)ws; ws += (size_t)16 * 16 * 8 * 2;
    float*          consts = (float*)ws;          ws += (size_t)8 * 4;
    float*          s_src  = (float*)ws;          ws += (size_t)N * 4 * 4;
    float*          s_dst  = (float*)ws;          ws += (size_t)N * 4 * 4;
    int*            head4  = (int*)ws;            ws += (size_t)N * 4 * 4;
    int4*           epkt   = (int4*)ws;           ws += (size_t)E * 16;

    const int zeroBlocks = (N * 4 + 1023) / 1024;   // 196
    k_prep<<<2 + zeroBlocks, 256, 0, stream>>>(Ww, Wb, att, Wb16, wsdB, consts, head4, N);

    const int gemmBlocks = ((N + 63) / 64) * 2;     // 1564
    k_mega<<<gemmBlocks, 256, 0, stream>>>(
        h, Wb16, wsdB, consts, Wb, zb16, s_src, s_dst, N);
    k_edge<<<(E + 255) / 256, 256, 0, stream>>>(src, dst, ef, att, s_src, s_dst,
                                                head4, epkt, E);
    k_agg_final<<<(N + 15) / 16, 256, 0, stream>>>(head4, epkt,
                                                   (const uint4*)zb16, lng, lnb, out, N);
}

// Round 13
// 125.506 us; speedup vs baseline: 1.3044x; 1.0223x over previous
//
#include <hip/hip_runtime.h>
#include <hip/hip_bf16.h>
#include <math.h>

typedef __attribute__((ext_vector_type(8))) short bf16x8;
typedef __attribute__((ext_vector_type(4))) float f32x4;

__device__ __forceinline__ unsigned short f2bf(float f) {
    unsigned u = __float_as_uint(f);
    unsigned r = ((u >> 16) & 1u) + 0x7fffu;   // RNE
    return (unsigned short)((u + r) >> 16);
}
__device__ __forceinline__ float bfL(unsigned u) { return __uint_as_float(u << 16); }
__device__ __forceinline__ float bfH(unsigned u) { return __uint_as_float(u & 0xffff0000u); }

#define SCORE_NPB 32   // nodes per score block (8 lanes/node)

// ---- prep: W->bf16 frags | scores (fp32 exact) | head8 init ----------------
__global__ __launch_bounds__(256) void k_prep(const float* __restrict__ W,
                                              const float* __restrict__ bias,
                                              const float* __restrict__ att,
                                              const float* __restrict__ h,
                                              unsigned short* __restrict__ Wb16,
                                              float* __restrict__ s_src,
                                              float* __restrict__ s_dst,
                                              int* __restrict__ head8,
                                              int N, int scoreBlocks) {
    const int t = threadIdx.x;
    const int bid = blockIdx.x;
    if (bid == 0) {
        // W -> bf16 MFMA fragment order (granule gi = kg*128 + row;
        // k = (kg>>2)*32 + (e>>2)*16 + (kg&3)*4 + (e&3))
#pragma unroll
        for (int q = 0; q < 8; ++q) {
            int gi = q * 256 + t;
            int kg = gi >> 7, row = gi & 127;
            int kbase = (kg >> 2) * 32 + (kg & 3) * 4;
            unsigned pk[4];
#pragma unroll
            for (int p = 0; p < 4; ++p) {
                int e0 = 2 * p, e1 = 2 * p + 1;
                float v0 = W[(size_t)row * 128 + kbase + (e0 >> 2) * 16 + (e0 & 3)];
                float v1 = W[(size_t)row * 128 + kbase + (e1 >> 2) * 16 + (e1 & 3)];
                pk[p] = ((unsigned)f2bf(v1) << 16) | f2bf(v0);
            }
            *reinterpret_cast<uint4*>(&Wb16[(size_t)gi * 8]) =
                make_uint4(pk[0], pk[1], pk[2], pk[3]);
        }
    } else if (bid <= scoreBlocks) {
        // fp32 score halves: fold wsd = W^T att in LDS, then dot with h
        __shared__ float wsdL[2][4][128];   // [isDst][head][k], 4 KB
        __shared__ float cs[8];
#pragma unroll
        for (int q = 0; q < 4; ++q) {
            int idx = q * 256 + t;          // 1024 entries
            int isD = idx >> 9, rem = idx & 511;
            int hd = rem >> 7, k = rem & 127;
            float w = 0.f;
            for (int j = 0; j < 32; ++j)
                w += W[(size_t)(hd * 32 + j) * 128 + k] * att[hd * 65 + isD * 32 + j];
            wsdL[isD][hd][k] = w;
        }
        if (t < 8) {
            int chd = t & 3, cIsD = t >> 2;
            float c = 0.f;
            for (int j = 0; j < 32; ++j)
                c += bias[chd * 32 + j] * att[chd * 65 + cIsD * 32 + j];
            cs[t] = c;
        }
        __syncthreads();
        int node = (bid - 1) * SCORE_NPB + (t >> 3);
        int p = t & 7;
        if (node < N) {
            const float* hp = h + (size_t)node * 128 + p * 16;
            float ss[4] = {0.f, 0.f, 0.f, 0.f}, sd[4] = {0.f, 0.f, 0.f, 0.f};
#pragma unroll
            for (int q = 0; q < 4; ++q) {
                float4 hv = *reinterpret_cast<const float4*>(hp + q * 4);
#pragma unroll
                for (int hd = 0; hd < 4; ++hd) {
                    const float* wa = &wsdL[0][hd][p * 16 + q * 4];
                    const float* wb = &wsdL[1][hd][p * 16 + q * 4];
                    ss[hd] += hv.x * wa[0] + hv.y * wa[1] + hv.z * wa[2] + hv.w * wa[3];
                    sd[hd] += hv.x * wb[0] + hv.y * wb[1] + hv.z * wb[2] + hv.w * wb[3];
                }
            }
#pragma unroll
            for (int off = 1; off < 8; off <<= 1)
#pragma unroll
                for (int hd = 0; hd < 4; ++hd) {
                    ss[hd] += __shfl_xor(ss[hd], off);
                    sd[hd] += __shfl_xor(sd[hd], off);
                }
            if (p == 0) {
                *reinterpret_cast<float4*>(&s_src[(size_t)node * 4]) =
                    make_float4(ss[0] + cs[0], ss[1] + cs[1], ss[2] + cs[2], ss[3] + cs[3]);
                *reinterpret_cast<float4*>(&s_dst[(size_t)node * 4]) =
                    make_float4(sd[0] + cs[4], sd[1] + cs[5], sd[2] + cs[6], sd[3] + cs[7]);
            }
        }
    } else {
        int i = ((bid - 1 - scoreBlocks) * 256 + t) * 4;
        if (i < N * 8)
            *reinterpret_cast<int4*>(&head8[i]) = make_int4(-1, -1, -1, -1);
    }
}

// ---- work: MFMA GEMM blocks + edge blocks (fused, independent) -------------
__global__ __launch_bounds__(256) void k_work(
        const float* __restrict__ h, const unsigned short* __restrict__ Wb16,
        const float* __restrict__ bias, unsigned short* __restrict__ zb16,
        const int* __restrict__ src, const int* __restrict__ dst,
        const float* __restrict__ ef, const float* __restrict__ att,
        const float* __restrict__ s_src, const float* __restrict__ s_dst,
        int* __restrict__ head8, int4* __restrict__ epkt,
        int N, int E, int gemmBlocks) {
    __shared__ short hS[16 * 64 * 8];    // 16 KB (gemm blocks only)
    const int t = threadIdx.x;
    const int bid = blockIdx.x;

    if (bid >= gemmBlocks) {
        // ---- edge: alpha (dense) + linked-list build (8 chains/node) ----
        int e = (bid - gemmBlocks) * 256 + t;
        if (e >= E) return;
        int s = src[e], d = dst[e];
        float fv = ef[e];
        float4 ss = *reinterpret_cast<const float4*>(&s_src[(size_t)s * 4]);
        float4 sd = *reinterpret_cast<const float4*>(&s_dst[(size_t)d * 4]);
        float aE0 = att[64], aE1 = att[129], aE2 = att[194], aE3 = att[259];
        float sc0 = ss.x + sd.x + fv * aE0;
        float sc1 = ss.y + sd.y + fv * aE1;
        float sc2 = ss.z + sd.z + fv * aE2;
        float sc3 = ss.w + sd.w + fv * aE3;
        sc0 = sc0 >= 0.f ? sc0 : 0.2f * sc0;  sc1 = sc1 >= 0.f ? sc1 : 0.2f * sc1;
        sc2 = sc2 >= 0.f ? sc2 : 0.2f * sc2;  sc3 = sc3 >= 0.f ? sc3 : 0.2f * sc3;
        float a0 = expf(fminf(fmaxf(sc0, -20.f), 20.f));
        float a1 = expf(fminf(fmaxf(sc1, -20.f), 20.f));
        float a2 = expf(fminf(fmaxf(sc2, -20.f), 20.f));
        float a3 = expf(fminf(fmaxf(sc3, -20.f), 20.f));
        int prev = atomicExch(&head8[(size_t)d * 8 + (e & 7)], e);
        epkt[e] = make_int4(s, prev,
            (int)(((unsigned)f2bf(a1) << 16) | f2bf(a0)),
            (int)(((unsigned)f2bf(a3) << 16) | f2bf(a2)));
        return;
    }

    // ---- GEMM block: 64 nodes x 64 cols (bid&1 selects col half) ----
    const int by = bid & 1;
    const int n0 = (bid >> 1) * 64;
    const int obase = by * 64;
#pragma unroll
    for (int q = 0; q < 8; ++q) {
        int f = q * 256 + t;
        int nd = f >> 5;
        int k4 = (f & 31) * 4;
        int ks = k4 >> 5, rr = k4 & 31;
        int half = rr >> 4, g = (rr & 15) >> 2;
        int kg = ks * 4 + g;
        int slot = kg * 64 + (nd ^ (kg & 7));
        int hn = n0 + nd; if (hn > N - 1) hn = N - 1;
        float4 v = *reinterpret_cast<const float4*>(&h[(size_t)hn * 128 + k4]);
        uint2 pk = make_uint2(((unsigned)f2bf(v.y) << 16) | f2bf(v.x),
                              ((unsigned)f2bf(v.w) << 16) | f2bf(v.z));
        *reinterpret_cast<uint2*>(&hS[slot * 8 + half * 4]) = pk;
    }
    __syncthreads();

    const int wv = t >> 6, l = t & 63;
    const int la = l & 15, lb = l >> 4;
    const int nbase = wv * 16;
    const int node = n0 + nbase + la;

    bf16x8 hfr[4];
#pragma unroll
    for (int ks = 0; ks < 4; ++ks) {
        int kg = ks * 4 + lb;
        int slot = kg * 64 + ((nbase + la) ^ (kg & 7));
        hfr[ks] = *reinterpret_cast<const bf16x8*>(&hS[slot * 8]);
    }

#pragma unroll
    for (int ot = 0; ot < 4; ++ot) {
        f32x4 acc = {0.f, 0.f, 0.f, 0.f};
#pragma unroll
        for (int ks = 0; ks < 4; ++ks) {
            int kg = ks * 4 + lb;
            bf16x8 wfr = *reinterpret_cast<const bf16x8*>(
                &Wb16[((size_t)kg * 128 + obase + ot * 16 + la) * 8]);
            acc = __builtin_amdgcn_mfma_f32_16x16x32_bf16(wfr, hfr[ks], acc, 0, 0, 0);
        }
        int colb = obase + ot * 16 + lb * 4;
        float4 bq = *reinterpret_cast<const float4*>(&bias[colb]);
        if (node < N) {
            uint2 pk = make_uint2(
                ((unsigned)f2bf(acc[1] + bq.y) << 16) | f2bf(acc[0] + bq.x),
                ((unsigned)f2bf(acc[3] + bq.w) << 16) | f2bf(acc[2] + bq.z));
            *reinterpret_cast<uint2*>(&zb16[(size_t)node * 128 + colb]) = pk;
        }
    }
}

// ---- fused: 8-chain walk aggregate + residual + LN + ELU -------------------
// 4 nodes per wave (16 lanes/node, 8 channels/lane); 8 chains per node.
__global__ __launch_bounds__(256) void k_agg_final(const int* __restrict__ head8,
                                                   const int4* __restrict__ epkt,
                                                   const uint4* __restrict__ zb4,
                                                   const float* __restrict__ g,
                                                   const float* __restrict__ bparm,
                                                   float* __restrict__ out, int N) {
    int wave = threadIdx.x >> 6, lane = threadIdx.x & 63;
    int l16 = lane & 15;
    int n = blockIdx.x * 16 + wave * 4 + (lane >> 4);
    if (n >= N) return;
    const int hd = l16 >> 2;
    int4 eha = *reinterpret_cast<const int4*>(&head8[(size_t)n * 8]);
    int4 ehb = *reinterpret_cast<const int4*>(&head8[(size_t)n * 8 + 4]);
    int e0 = eha.x, e1 = eha.y, e2 = eha.z, e3 = eha.w;
    int e4 = ehb.x, e5 = ehb.y, e6 = ehb.z, e7 = ehb.w;
    float A0 = 0.f, A1 = 0.f, A2 = 0.f, A3 = 0.f;
    float A4 = 0.f, A5 = 0.f, A6 = 0.f, A7 = 0.f;
    float da = 0.f;
#define UNPK(P, AV) { unsigned u = (hd & 2) ? (unsigned)(P).w : (unsigned)(P).z; \
    AV = (hd & 1) ? bfH(u) : bfL(u); }
#define STEP(EV) if (EV != -1) { \
        int4 p = epkt[EV]; \
        uint4 q = zb4[(size_t)p.x * 16 + l16]; \
        float a; UNPK(p, a) \
        A0 += bfL(q.x) * a; A1 += bfH(q.x) * a; \
        A2 += bfL(q.y) * a; A3 += bfH(q.y) * a; \
        A4 += bfL(q.z) * a; A5 += bfH(q.z) * a; \
        A6 += bfL(q.w) * a; A7 += bfH(q.w) * a; \
        da += a; EV = p.y; }
    while ((((e0 & e1) & (e2 & e3)) & ((e4 & e5) & (e6 & e7))) != -1) {
        STEP(e0) STEP(e1) STEP(e2) STEP(e3)
        STEP(e4) STEP(e5) STEP(e6) STEP(e7)
    }
#undef STEP
#undef UNPK

    float inv = 1.f / (da + 1e-6f);
    uint4 qz = zb4[(size_t)n * 16 + l16];
    float x0 = A0 * inv + bfL(qz.x);
    float x1 = A1 * inv + bfH(qz.x);
    float x2 = A2 * inv + bfL(qz.y);
    float x3 = A3 * inv + bfH(qz.y);
    float x4 = A4 * inv + bfL(qz.z);
    float x5 = A5 * inv + bfH(qz.z);
    float x6 = A6 * inv + bfL(qz.w);
    float x7 = A7 * inv + bfH(qz.w);
    float s = ((x0 + x1) + (x2 + x3)) + ((x4 + x5) + (x6 + x7));
#pragma unroll
    for (int off = 1; off < 16; off <<= 1) s += __shfl_xor(s, off);
    float mu = s * (1.f / 128.f);
    float d0 = x0 - mu, d1 = x1 - mu, d2 = x2 - mu, d3 = x3 - mu;
    float d4 = x4 - mu, d5 = x5 - mu, d6 = x6 - mu, d7 = x7 - mu;
    float q = ((d0 * d0 + d1 * d1) + (d2 * d2 + d3 * d3))
            + ((d4 * d4 + d5 * d5) + (d6 * d6 + d7 * d7));
#pragma unroll
    for (int off = 1; off < 16; off <<= 1) q += __shfl_xor(q, off);
    float rstd = rsqrtf(q * (1.f / 128.f) + 1e-5f);
    const int c = l16 * 8;
    float4 g0 = *reinterpret_cast<const float4*>(&g[c]);
    float4 g1 = *reinterpret_cast<const float4*>(&g[c + 4]);
    float4 b0 = *reinterpret_cast<const float4*>(&bparm[c]);
    float4 b1 = *reinterpret_cast<const float4*>(&bparm[c + 4]);
    float y0 = d0 * rstd * g0.x + b0.x;
    float y1 = d1 * rstd * g0.y + b0.y;
    float y2 = d2 * rstd * g0.z + b0.z;
    float y3 = d3 * rstd * g0.w + b0.w;
    float y4 = d4 * rstd * g1.x + b1.x;
    float y5 = d5 * rstd * g1.y + b1.y;
    float y6 = d6 * rstd * g1.z + b1.z;
    float y7 = d7 * rstd * g1.w + b1.w;
    y0 = y0 > 0.f ? y0 : expf(y0) - 1.f;
    y1 = y1 > 0.f ? y1 : expf(y1) - 1.f;
    y2 = y2 > 0.f ? y2 : expf(y2) - 1.f;
    y3 = y3 > 0.f ? y3 : expf(y3) - 1.f;
    y4 = y4 > 0.f ? y4 : expf(y4) - 1.f;
    y5 = y5 > 0.f ? y5 : expf(y5) - 1.f;
    y6 = y6 > 0.f ? y6 : expf(y6) - 1.f;
    y7 = y7 > 0.f ? y7 : expf(y7) - 1.f;
    *reinterpret_cast<float4*>(&out[(size_t)n * 128 + c]) = make_float4(y0, y1, y2, y3);
    *reinterpret_cast<float4*>(&out[(size_t)n * 128 + c + 4]) = make_float4(y4, y5, y6, y7);
}

extern "C" void kernel_launch(void* const* d_in, const int* in_sizes, int n_in,
                              void* d_out, int out_size, void* d_ws, size_t ws_size,
                              hipStream_t stream) {
    const float* h   = (const float*)d_in[0];
    const int*   ei  = (const int*)d_in[1];
    const float* ef  = (const float*)d_in[2];
    const float* Ww  = (const float*)d_in[3];
    const float* Wb  = (const float*)d_in[4];
    const float* att = (const float*)d_in[5];
    const float* lng = (const float*)d_in[6];
    const float* lnb = (const float*)d_in[7];
    float* out = (float*)d_out;

    const int N = in_sizes[0] / 128;   // 50000
    const int E = in_sizes[1] / 2;     // 800000
    const int* src = ei;
    const int* dst = ei + E;

    char* ws = (char*)d_ws;
    unsigned short* zb16   = (unsigned short*)ws; ws += (size_t)N * 128 * 2;
    unsigned short* Wb16   = (unsigned short*)ws; ws += (size_t)128 * 128 * 2;
    float*          s_src  = (float*)ws;          ws += (size_t)N * 4 * 4;
    float*          s_dst  = (float*)ws;          ws += (size_t)N * 4 * 4;
    int*            head8  = (int*)ws;            ws += (size_t)N * 8 * 4;
    int4*           epkt   = (int4*)ws;           ws += (size_t)E * 16;

    const int scoreBlocks = (N + SCORE_NPB - 1) / SCORE_NPB;   // 1563
    const int headBlocks  = (N * 8 / 4 + 255) / 256;           // 391
    k_prep<<<1 + scoreBlocks + headBlocks, 256, 0, stream>>>(
        Ww, Wb, att, h, Wb16, s_src, s_dst, head8, N, scoreBlocks);

    const int gemmBlocks = ((N + 63) / 64) * 2;   // 1564
    const int edgeBlocks = (E + 255) / 256;       // 3125
    k_work<<<gemmBlocks + edgeBlocks, 256, 0, stream>>>(
        h, Wb16, Wb, zb16, src, dst, ef, att, s_src, s_dst, head8, epkt,
        N, E, gemmBlocks);
    k_agg_final<<<(N + 15) / 16, 256, 0, stream>>>(head8, epkt,
                                                   (const uint4*)zb16, lng, lnb, out, N);
}

// Round 14
// 116.691 us; speedup vs baseline: 1.4030x; 1.0755x over previous
//
#include <hip/hip_runtime.h>
#include <hip/hip_bf16.h>
#include <math.h>

typedef __attribute__((ext_vector_type(8))) short bf16x8;
typedef __attribute__((ext_vector_type(4))) float f32x4;

__device__ __forceinline__ unsigned short f2bf(float f) {
    unsigned u = __float_as_uint(f);
    unsigned r = ((u >> 16) & 1u) + 0x7fffu;   // RNE
    return (unsigned short)((u + r) >> 16);
}
__device__ __forceinline__ float bfL(unsigned u) { return __uint_as_float(u << 16); }
__device__ __forceinline__ float bfH(unsigned u) { return __uint_as_float(u & 0xffff0000u); }

#define SCORE_NPB 32   // nodes per score block (8 lanes/node)

// ---- prep: W->bf16 frags | scores (fp32 exact) | head4 init ----------------
__global__ __launch_bounds__(256) void k_prep(const float* __restrict__ W,
                                              const float* __restrict__ bias,
                                              const float* __restrict__ att,
                                              const float* __restrict__ h,
                                              unsigned short* __restrict__ Wb16,
                                              float* __restrict__ s_src,
                                              float* __restrict__ s_dst,
                                              int* __restrict__ head4,
                                              int N, int scoreBlocks) {
    const int t = threadIdx.x;
    const int bid = blockIdx.x;
    if (bid == 0) {
        // W -> bf16 MFMA fragment order (granule gi = kg*128 + row;
        // k = (kg>>2)*32 + (e>>2)*16 + (kg&3)*4 + (e&3))
#pragma unroll
        for (int q = 0; q < 8; ++q) {
            int gi = q * 256 + t;
            int kg = gi >> 7, row = gi & 127;
            int kbase = (kg >> 2) * 32 + (kg & 3) * 4;
            unsigned pk[4];
#pragma unroll
            for (int p = 0; p < 4; ++p) {
                int e0 = 2 * p, e1 = 2 * p + 1;
                float v0 = W[(size_t)row * 128 + kbase + (e0 >> 2) * 16 + (e0 & 3)];
                float v1 = W[(size_t)row * 128 + kbase + (e1 >> 2) * 16 + (e1 & 3)];
                pk[p] = ((unsigned)f2bf(v1) << 16) | f2bf(v0);
            }
            *reinterpret_cast<uint4*>(&Wb16[(size_t)gi * 8]) =
                make_uint4(pk[0], pk[1], pk[2], pk[3]);
        }
    } else if (bid <= scoreBlocks) {
        // fp32 score halves: fold wsd = W^T att in LDS, then dot with h
        __shared__ float wsdL[2][4][128];   // [isDst][head][k], 4 KB
        __shared__ float cs[8];
#pragma unroll
        for (int q = 0; q < 4; ++q) {
            int idx = q * 256 + t;          // 1024 entries
            int isD = idx >> 9, rem = idx & 511;
            int hd = rem >> 7, k = rem & 127;
            float w = 0.f;
            for (int j = 0; j < 32; ++j)
                w += W[(size_t)(hd * 32 + j) * 128 + k] * att[hd * 65 + isD * 32 + j];
            wsdL[isD][hd][k] = w;
        }
        if (t < 8) {
            int chd = t & 3, cIsD = t >> 2;
            float c = 0.f;
            for (int j = 0; j < 32; ++j)
                c += bias[chd * 32 + j] * att[chd * 65 + cIsD * 32 + j];
            cs[t] = c;
        }
        __syncthreads();
        int node = (bid - 1) * SCORE_NPB + (t >> 3);
        int p = t & 7;
        if (node < N) {
            const float* hp = h + (size_t)node * 128 + p * 16;
            float ss[4] = {0.f, 0.f, 0.f, 0.f}, sd[4] = {0.f, 0.f, 0.f, 0.f};
#pragma unroll
            for (int q = 0; q < 4; ++q) {
                float4 hv = *reinterpret_cast<const float4*>(hp + q * 4);
#pragma unroll
                for (int hd = 0; hd < 4; ++hd) {
                    const float* wa = &wsdL[0][hd][p * 16 + q * 4];
                    const float* wb = &wsdL[1][hd][p * 16 + q * 4];
                    ss[hd] += hv.x * wa[0] + hv.y * wa[1] + hv.z * wa[2] + hv.w * wa[3];
                    sd[hd] += hv.x * wb[0] + hv.y * wb[1] + hv.z * wb[2] + hv.w * wb[3];
                }
            }
#pragma unroll
            for (int off = 1; off < 8; off <<= 1)
#pragma unroll
                for (int hd = 0; hd < 4; ++hd) {
                    ss[hd] += __shfl_xor(ss[hd], off);
                    sd[hd] += __shfl_xor(sd[hd], off);
                }
            if (p == 0) {
                *reinterpret_cast<float4*>(&s_src[(size_t)node * 4]) =
                    make_float4(ss[0] + cs[0], ss[1] + cs[1], ss[2] + cs[2], ss[3] + cs[3]);
                *reinterpret_cast<float4*>(&s_dst[(size_t)node * 4]) =
                    make_float4(sd[0] + cs[4], sd[1] + cs[5], sd[2] + cs[6], sd[3] + cs[7]);
            }
        }
    } else {
        int i = ((bid - 1 - scoreBlocks) * 256 + t) * 4;
        if (i < N * 4)
            *reinterpret_cast<int4*>(&head4[i]) = make_int4(-1, -1, -1, -1);
    }
}

// ---- work: MFMA GEMM blocks + edge blocks (fused, independent) -------------
__global__ __launch_bounds__(256) void k_work(
        const float* __restrict__ h, const unsigned short* __restrict__ Wb16,
        const float* __restrict__ bias, unsigned short* __restrict__ zb16,
        const int* __restrict__ src, const int* __restrict__ dst,
        const float* __restrict__ ef, const float* __restrict__ att,
        const float* __restrict__ s_src, const float* __restrict__ s_dst,
        int* __restrict__ head4, int4* __restrict__ epkt,
        int N, int E, int gemmBlocks) {
    __shared__ short hS[16 * 64 * 8];    // 16 KB (gemm blocks only)
    const int t = threadIdx.x;
    const int bid = blockIdx.x;

    if (bid >= gemmBlocks) {
        // ---- edge: alpha (dense) + linked-list build (4 chains/node) ----
        int e = (bid - gemmBlocks) * 256 + t;
        if (e >= E) return;
        int s = src[e], d = dst[e];
        float fv = ef[e];
        float4 ss = *reinterpret_cast<const float4*>(&s_src[(size_t)s * 4]);
        float4 sd = *reinterpret_cast<const float4*>(&s_dst[(size_t)d * 4]);
        float aE0 = att[64], aE1 = att[129], aE2 = att[194], aE3 = att[259];
        float sc0 = ss.x + sd.x + fv * aE0;
        float sc1 = ss.y + sd.y + fv * aE1;
        float sc2 = ss.z + sd.z + fv * aE2;
        float sc3 = ss.w + sd.w + fv * aE3;
        sc0 = sc0 >= 0.f ? sc0 : 0.2f * sc0;  sc1 = sc1 >= 0.f ? sc1 : 0.2f * sc1;
        sc2 = sc2 >= 0.f ? sc2 : 0.2f * sc2;  sc3 = sc3 >= 0.f ? sc3 : 0.2f * sc3;
        float a0 = expf(fminf(fmaxf(sc0, -20.f), 20.f));
        float a1 = expf(fminf(fmaxf(sc1, -20.f), 20.f));
        float a2 = expf(fminf(fmaxf(sc2, -20.f), 20.f));
        float a3 = expf(fminf(fmaxf(sc3, -20.f), 20.f));
        int prev = atomicExch(&head4[(size_t)d * 4 + (e & 3)], e);
        epkt[e] = make_int4(s, prev,
            (int)(((unsigned)f2bf(a1) << 16) | f2bf(a0)),
            (int)(((unsigned)f2bf(a3) << 16) | f2bf(a2)));
        return;
    }

    // ---- GEMM block: 64 nodes x 64 cols (bid&1 selects col half) ----
    const int by = bid & 1;
    const int n0 = (bid >> 1) * 64;
    const int obase = by * 64;
#pragma unroll
    for (int q = 0; q < 8; ++q) {
        int f = q * 256 + t;
        int nd = f >> 5;
        int k4 = (f & 31) * 4;
        int ks = k4 >> 5, rr = k4 & 31;
        int half = rr >> 4, g = (rr & 15) >> 2;
        int kg = ks * 4 + g;
        int slot = kg * 64 + (nd ^ (kg & 7));
        int hn = n0 + nd; if (hn > N - 1) hn = N - 1;
        float4 v = *reinterpret_cast<const float4*>(&h[(size_t)hn * 128 + k4]);
        uint2 pk = make_uint2(((unsigned)f2bf(v.y) << 16) | f2bf(v.x),
                              ((unsigned)f2bf(v.w) << 16) | f2bf(v.z));
        *reinterpret_cast<uint2*>(&hS[slot * 8 + half * 4]) = pk;
    }
    __syncthreads();

    const int wv = t >> 6, l = t & 63;
    const int la = l & 15, lb = l >> 4;
    const int nbase = wv * 16;
    const int node = n0 + nbase + la;

    bf16x8 hfr[4];
#pragma unroll
    for (int ks = 0; ks < 4; ++ks) {
        int kg = ks * 4 + lb;
        int slot = kg * 64 + ((nbase + la) ^ (kg & 7));
        hfr[ks] = *reinterpret_cast<const bf16x8*>(&hS[slot * 8]);
    }

#pragma unroll
    for (int ot = 0; ot < 4; ++ot) {
        f32x4 acc = {0.f, 0.f, 0.f, 0.f};
#pragma unroll
        for (int ks = 0; ks < 4; ++ks) {
            int kg = ks * 4 + lb;
            bf16x8 wfr = *reinterpret_cast<const bf16x8*>(
                &Wb16[((size_t)kg * 128 + obase + ot * 16 + la) * 8]);
            acc = __builtin_amdgcn_mfma_f32_16x16x32_bf16(wfr, hfr[ks], acc, 0, 0, 0);
        }
        int colb = obase + ot * 16 + lb * 4;
        float4 bq = *reinterpret_cast<const float4*>(&bias[colb]);
        if (node < N) {
            uint2 pk = make_uint2(
                ((unsigned)f2bf(acc[1] + bq.y) << 16) | f2bf(acc[0] + bq.x),
                ((unsigned)f2bf(acc[3] + bq.w) << 16) | f2bf(acc[2] + bq.z));
            *reinterpret_cast<uint2*>(&zb16[(size_t)node * 128 + colb]) = pk;
        }
    }
}

// ---- fused: 4-chain walk aggregate + residual + LN + ELU -------------------
// 8 nodes per wave (8 lanes/node, 16 channels/lane); 4 chains per node.
__global__ __launch_bounds__(256) void k_agg_final(const int* __restrict__ head4,
                                                   const int4* __restrict__ epkt,
                                                   const uint4* __restrict__ zb4,
                                                   const float* __restrict__ g,
                                                   const float* __restrict__ bparm,
                                                   float* __restrict__ out, int N) {
    int wave = threadIdx.x >> 6, lane = threadIdx.x & 63;
    int l8 = lane & 7;
    int n = blockIdx.x * 32 + wave * 8 + (lane >> 3);
    if (n >= N) return;
    const int hd = l8 >> 1;             // head of channels l8*16..+15
    int4 eh = *reinterpret_cast<const int4*>(&head4[(size_t)n * 4]);
    int e0 = eh.x, e1 = eh.y, e2 = eh.z, e3 = eh.w;
    float X0 = 0.f, X1 = 0.f, X2 = 0.f, X3 = 0.f;
    float X4 = 0.f, X5 = 0.f, X6 = 0.f, X7 = 0.f;
    float X8 = 0.f, X9 = 0.f, Xa = 0.f, Xb = 0.f;
    float Xc = 0.f, Xd = 0.f, Xe = 0.f, Xf = 0.f;
    float da = 0.f;
#define UNPK(P, AV) { unsigned u = (hd & 2) ? (unsigned)(P).w : (unsigned)(P).z; \
    AV = (hd & 1) ? bfH(u) : bfL(u); }
#define STEP(EV) if (EV != -1) { \
        int4 p = epkt[EV]; \
        uint4 q0 = zb4[(size_t)p.x * 16 + l8 * 2]; \
        uint4 q1 = zb4[(size_t)p.x * 16 + l8 * 2 + 1]; \
        float a; UNPK(p, a) \
        X0 += bfL(q0.x) * a; X1 += bfH(q0.x) * a; \
        X2 += bfL(q0.y) * a; X3 += bfH(q0.y) * a; \
        X4 += bfL(q0.z) * a; X5 += bfH(q0.z) * a; \
        X6 += bfL(q0.w) * a; X7 += bfH(q0.w) * a; \
        X8 += bfL(q1.x) * a; X9 += bfH(q1.x) * a; \
        Xa += bfL(q1.y) * a; Xb += bfH(q1.y) * a; \
        Xc += bfL(q1.z) * a; Xd += bfH(q1.z) * a; \
        Xe += bfL(q1.w) * a; Xf += bfH(q1.w) * a; \
        da += a; EV = p.y; }
    while (((e0 & e1) & (e2 & e3)) != -1) {
        STEP(e0) STEP(e1) STEP(e2) STEP(e3)
    }
#undef STEP
#undef UNPK

    float inv = 1.f / (da + 1e-6f);
    uint4 qz0 = zb4[(size_t)n * 16 + l8 * 2];
    uint4 qz1 = zb4[(size_t)n * 16 + l8 * 2 + 1];
    float x0 = X0 * inv + bfL(qz0.x), x1 = X1 * inv + bfH(qz0.x);
    float x2 = X2 * inv + bfL(qz0.y), x3 = X3 * inv + bfH(qz0.y);
    float x4 = X4 * inv + bfL(qz0.z), x5 = X5 * inv + bfH(qz0.z);
    float x6 = X6 * inv + bfL(qz0.w), x7 = X7 * inv + bfH(qz0.w);
    float x8 = X8 * inv + bfL(qz1.x), x9 = X9 * inv + bfH(qz1.x);
    float xa = Xa * inv + bfL(qz1.y), xb = Xb * inv + bfH(qz1.y);
    float xc = Xc * inv + bfL(qz1.z), xd = Xd * inv + bfH(qz1.z);
    float xe = Xe * inv + bfL(qz1.w), xf = Xf * inv + bfH(qz1.w);
    float s = (((x0 + x1) + (x2 + x3)) + ((x4 + x5) + (x6 + x7)))
            + (((x8 + x9) + (xa + xb)) + ((xc + xd) + (xe + xf)));
#pragma unroll
    for (int off = 1; off < 8; off <<= 1) s += __shfl_xor(s, off);
    float mu = s * (1.f / 128.f);
    float d0 = x0 - mu, d1 = x1 - mu, d2 = x2 - mu, d3 = x3 - mu;
    float d4 = x4 - mu, d5 = x5 - mu, d6 = x6 - mu, d7 = x7 - mu;
    float d8 = x8 - mu, d9 = x9 - mu, dA = xa - mu, dB = xb - mu;
    float dC = xc - mu, dD = xd - mu, dE = xe - mu, dF = xf - mu;
    float q = (((d0 * d0 + d1 * d1) + (d2 * d2 + d3 * d3))
             + ((d4 * d4 + d5 * d5) + (d6 * d6 + d7 * d7)))
            + (((d8 * d8 + d9 * d9) + (dA * dA + dB * dB))
             + ((dC * dC + dD * dD) + (dE * dE + dF * dF)));
#pragma unroll
    for (int off = 1; off < 8; off <<= 1) q += __shfl_xor(q, off);
    float rstd = rsqrtf(q * (1.f / 128.f) + 1e-5f);
    const int c = l8 * 16;
    float dv[16] = {d0, d1, d2, d3, d4, d5, d6, d7, d8, d9, dA, dB, dC, dD, dE, dF};
#pragma unroll
    for (int qb = 0; qb < 4; ++qb) {
        float4 gg = *reinterpret_cast<const float4*>(&g[c + qb * 4]);
        float4 bb = *reinterpret_cast<const float4*>(&bparm[c + qb * 4]);
        float y0 = dv[qb * 4 + 0] * rstd * gg.x + bb.x;
        float y1 = dv[qb * 4 + 1] * rstd * gg.y + bb.y;
        float y2 = dv[qb * 4 + 2] * rstd * gg.z + bb.z;
        float y3 = dv[qb * 4 + 3] * rstd * gg.w + bb.w;
        y0 = y0 > 0.f ? y0 : expf(y0) - 1.f;
        y1 = y1 > 0.f ? y1 : expf(y1) - 1.f;
        y2 = y2 > 0.f ? y2 : expf(y2) - 1.f;
        y3 = y3 > 0.f ? y3 : expf(y3) - 1.f;
        *reinterpret_cast<float4*>(&out[(size_t)n * 128 + c + qb * 4]) =
            make_float4(y0, y1, y2, y3);
    }
}

extern "C" void kernel_launch(void* const* d_in, const int* in_sizes, int n_in,
                              void* d_out, int out_size, void* d_ws, size_t ws_size,
                              hipStream_t stream) {
    const float* h   = (const float*)d_in[0];
    const int*   ei  = (const int*)d_in[1];
    const float* ef  = (const float*)d_in[2];
    const float* Ww  = (const float*)d_in[3];
    const float* Wb  = (const float*)d_in[4];
    const float* att = (const float*)d_in[5];
    const float* lng = (const float*)d_in[6];
    const float* lnb = (const float*)d_in[7];
    float* out = (float*)d_out;

    const int N = in_sizes[0] / 128;   // 50000
    const int E = in_sizes[1] / 2;     // 800000
    const int* src = ei;
    const int* dst = ei + E;

    char* ws = (char*)d_ws;
    unsigned short* zb16   = (unsigned short*)ws; ws += (size_t)N * 128 * 2;
    unsigned short* Wb16   = (unsigned short*)ws; ws += (size_t)128 * 128 * 2;
    float*          s_src  = (float*)ws;          ws += (size_t)N * 4 * 4;
    float*          s_dst  = (float*)ws;          ws += (size_t)N * 4 * 4;
    int*            head4  = (int*)ws;            ws += (size_t)N * 4 * 4;
    int4*           epkt   = (int4*)ws;           ws += (size_t)E * 16;

    const int scoreBlocks = (N + SCORE_NPB - 1) / SCORE_NPB;   // 1563
    const int headBlocks  = (N + 255) / 256;                   // 196
    k_prep<<<1 + scoreBlocks + headBlocks, 256, 0, stream>>>(
        Ww, Wb, att, h, Wb16, s_src, s_dst, head4, N, scoreBlocks);

    const int gemmBlocks = ((N + 63) / 64) * 2;   // 1564
    const int edgeBlocks = (E + 255) / 256;       // 3125
    k_work<<<gemmBlocks + edgeBlocks, 256, 0, stream>>>(
        h, Wb16, Wb, zb16, src, dst, ef, att, s_src, s_dst, head4, epkt,
        N, E, gemmBlocks);
    k_agg_final<<<(N + 31) / 32, 256, 0, stream>>>(head4, epkt,
                                                   (const uint4*)zb16, lng, lnb, out, N);
}